// Round 8
// baseline (505.577 us; speedup 1.0000x reference)
//
#include <hip/hip_runtime.h>

typedef __attribute__((ext_vector_type(8))) short v8s;
typedef __attribute__((ext_vector_type(4))) float v4f;
typedef unsigned short u16;

#define DINL static __device__ __forceinline__

DINL float b2f(u16 u){ union { unsigned uu; float ff; } x; x.uu = ((unsigned)u)<<16; return x.ff; }
DINL u16 f2b(float f){ union { float ff; unsigned uu; } x; x.ff = f; unsigned r = x.uu + 0x7FFFu + ((x.uu>>16)&1u); return (u16)(r>>16); }
DINL u16 f2b_hu(float f){ union { float ff; unsigned uu; } x; x.ff = f; return (u16)((x.uu + 0x8000u)>>16); }
DINL float sigm(float x){ return 1.0f/(1.0f+__expf(-x)); }
DINL float tanh_(float x){ return 2.0f/(1.0f+__expf(-2.0f*x)) - 1.0f; }
DINL float ld(const void* p, int i, int isf){
    return isf ? ((const float*)p)[i] : b2f(((const u16*)p)[i]);
}
DINL void g2lds16(const u16* g, u16* l){
    __builtin_amdgcn_global_load_lds(
        (const __attribute__((address_space(1))) unsigned int*)g,
        (__attribute__((address_space(3))) unsigned int*)l, 16, 0, 0);
}
DINL int detect_isf(const void* obs_speed){
    const u16* p = (const u16*)obs_speed;
    int f = 0;
    for (int i = 0; i < 16; ++i){
        u16 v = p[2*i];
        if ((v & 0x8000u) || v > 0x3F80u) f = 1;
    }
    return f;
}

// ---- workspace byte offsets ----
#define FLAG_OFF 0x000000
#define AUX_OFF  0x000100
#define ENCF_OFF 0x010000
#define DECF_OFF 0x020000
#define CW2T_OFF 0x050000
#define W2T_OFF  0x090000   // dead after k_pool; decH overlays
#define DECH_OFF 0x090000
#define CW1T_OFF 0x190000
#define IT_OFF   0x3D0000
#define IR_OFF   0x3F0000
#define IS_OFF   0x410000
#define INZ_OFF  0x420000
#define IW1H_OFF 0x430000
#define SM_OFF   0x440000
#define CTX_OFF  0x450000   // ctx_in 4096x1152 bf16
#define AV_OFF   0xD50000   // Avec bf16 (dead after k_pool); c1 overlays
#define BIG_NEED 0x1550000  // AV_OFF + 8MB single-pass c1

#define SM_EEW 0
#define SM_EEB 128
#define SM_ENB 192
#define SM_DEW 448
#define SM_DEB 640
#define SM_DNB 704
#define SM_H2W 1216
#define SM_H2B 1472
#define SM_SEW 1536
#define SM_SEB 2048

// ---------------- unified prep kernel ----------------
DINL void trans_tile(const void* in, u16* out, int K, int N, int isf,
                     int bx, int by, int t, float tile[64][65])
{
    const int nbase = bx*64, kbase = by*64;
    const int c = t & 63, r0 = (t >> 6)*16;
    for (int rep = 0; rep < 16; ++rep){
        int r = r0 + rep;
        int n = nbase + c;
        float v = 0.f;
        if (n < N) v = ld(in, (kbase + r)*N + n, isf);
        tile[r][c] = v;
    }
    __syncthreads();
    for (int rep = 0; rep < 16; ++rep){
        int r = r0 + rep;
        out[(size_t)(nbase + r)*K + kbase + c] = f2b(tile[c][r]);
    }
}

__global__ __launch_bounds__(256) void k_prep(
    const void* obs_traj, const void* obs_rel, const void* obs_speed, const void* noise,
    const void* eeW, const void* eeB, const void* enc_Wih, const void* enc_Whh, const void* encB,
    const void* spW, const void* spB, const void* spdW, const void* spdB,
    const void* pool_l1_W, const void* l1B, const void* bn1g, const void* bn1b,
    const void* pool_l2_W, const void* l2b, const void* bn2g, const void* bn2b,
    const void* seW, const void* seB,
    const void* ctx_l1_W, const void* c1b, const void* cbn1g, const void* cbn1b,
    const void* ctx_l2_W, const void* c2b, const void* cbn2g, const void* cbn2b,
    const void* deW, const void* deB, const void* dec_Wih, const void* dec_Whh, const void* decB,
    const void* h2W, const void* h2B,
    int* flag, float* AUX,
    u16* IT, u16* IR, u16* IS, u16* INZ, u16* IW1H, u16* SM,
    u16* W2T, u16* cW1T, u16* cW2T, u16* encF, u16* decF)
{
    __shared__ float tile[64][65];
    __shared__ int sisf;
    const int t = threadIdx.x;
    if (t == 0){
        int f = detect_isf(obs_speed);
        sisf = f;
        if (blockIdx.x == 0) *flag = f;
    }
    __syncthreads();
    const int isf = sisf;
    int bid = blockIdx.x;
    if (bid < 905){
        int idx = bid*256 + t;
        if (idx < 65536){ IT[idx] = f2b(ld(obs_traj, idx, isf)); return; }
        idx -= 65536;
        if (idx < 65536){ IR[idx] = f2b(ld(obs_rel, idx, isf)); return; }
        idx -= 65536;
        if (idx < 32768){ IS[idx] = f2b(ld(obs_speed, idx, isf)); return; }
        idx -= 32768;
        if (idx < 32768){ INZ[idx] = f2b(ld(noise, idx, isf)); return; }
        idx -= 32768;
        if (idx < 32768){ IW1H[idx] = f2b(ld(pool_l1_W, idx + 32768, isf)); return; }
        idx -= 32768;
        if (idx < 128){ SM[SM_EEW + idx] = f2b(ld(eeW, idx, isf)); return; }
        idx -= 128;
        if (idx < 64){ SM[SM_EEB + idx] = f2b(ld(eeB, idx, isf)); return; }
        idx -= 64;
        if (idx < 256){ SM[SM_ENB + idx] = f2b(ld(encB, idx, isf)); return; }
        idx -= 256;
        if (idx < 192){ SM[SM_DEW + idx] = f2b(ld(deW, idx, isf)); return; }
        idx -= 192;
        if (idx < 64){ SM[SM_DEB + idx] = f2b(ld(deB, idx, isf)); return; }
        idx -= 64;
        if (idx < 512){ SM[SM_DNB + idx] = f2b(ld(decB, idx, isf)); return; }
        idx -= 512;
        if (idx < 256){ SM[SM_H2W + idx] = f2b(ld(h2W, idx, isf)); return; }
        idx -= 256;
        if (idx < 2){ SM[SM_H2B + idx] = f2b(ld(h2B, idx, isf)); return; }
        idx -= 2;
        if (idx < 512){ SM[SM_SEW + idx] = f2b(ld(seW, idx, isf)); return; }
        idx -= 512;
        if (idx < 64){ SM[SM_SEB + idx] = f2b(ld(seB, idx, isf)); return; }
        return;
    }
    bid -= 905;
    if (bid < 512){
        int idx = bid*256 + t;
        if (idx < 32768){
            int jj = idx&7, lane = (idx>>3)&63, kcnf = idx>>9;
            int kc = kcnf&3, nf = kcnf>>2;
            int k = kc*32 + (lane>>4)*8 + jj, n = nf*16 + (lane&15);
            encF[idx] = (k < 64) ? f2b(ld(enc_Wih, k*256+n, isf)) : f2b(ld(enc_Whh, (k-64)*256+n, isf));
        } else {
            idx -= 32768;
            int jj = idx&7, lane = (idx>>3)&63, kcnf = idx>>9;
            int kc = kcnf % 6, nf = kcnf / 6;
            int k = kc*32 + (lane>>4)*8 + jj, n = nf*16 + (lane&15);
            decF[idx] = (k < 64) ? f2b(ld(dec_Wih, k*512+n, isf)) : f2b(ld(dec_Whh, (k-64)*512+n, isf));
        }
        return;
    }
    bid -= 512;
    if (bid < 128){ trans_tile(pool_l2_W, W2T, 512, 1024, isf, bid & 15, bid >> 4, t, tile); return; }
    bid -= 128;
    if (bid < 288){ trans_tile(ctx_l1_W, cW1T, 1152, 1024, isf, bid & 15, bid >> 4, t, tile); return; }
    bid -= 288;
    if (bid < 32){ trans_tile(ctx_l2_W, cW2T, 1024, 120, isf, bid & 1, bid >> 1, t, tile); return; }
    bid -= 32;
    {
        int idx = bid*256 + t;
        if (idx < 512){
            int c = idx;
            float m0 = 0.f, m1 = 0.f, qv = 0.f, cv = 0.f;
            for (int e = 0; e < 64; ++e){
                float w1a = ld(pool_l1_W, e*512 + c, isf);
                m0 += ld(spW, e, isf)*w1a;
                m1 += ld(spW, 64+e, isf)*w1a;
                cv += ld(spB, e, isf)*w1a;
                float w1c = ld(pool_l1_W, (128+e)*512 + c, isf);
                qv += ld(spdW, e, isf)*w1c;
                cv += ld(spdB, e, isf)*w1c;
            }
            cv += ld(l1B, c, isf);
            float g1 = ld(bn1g, c, isf), bb1 = ld(bn1b, c, isf);
            AUX[c] = m0; AUX[512+c] = m1; AUX[1024+c] = qv; AUX[1536+c] = cv;
            AUX[2048+c] = g1; AUX[2560+c] = bb1;
            AUX[3072+c] = g1*m0; AUX[3584+c] = g1*m1;
            return;
        }
        idx -= 512;
        if (idx < 1024){
            float g = ld(bn2g, idx, isf);
            AUX[4096+idx] = g; AUX[5120+idx] = ld(l2b, idx, isf)*g + ld(bn2b, idx, isf);
            return;
        }
        idx -= 1024;
        if (idx < 1024){
            float g = ld(cbn1g, idx, isf);
            AUX[6144+idx] = g; AUX[7168+idx] = ld(c1b, idx, isf)*g + ld(cbn1b, idx, isf);
            return;
        }
        idx -= 1024;
        if (idx < 128){
            int c = idx;
            float g  = (c < 120) ? ld(cbn2g, c, isf) : 1.f;
            float bb = (c < 120) ? (ld(c2b, c, isf)*g + ld(cbn2b, c, isf)) : 0.f;
            AUX[8192+c] = g; AUX[8320+c] = bb;
        }
    }
}

// ---------------- encoder LSTM (16 peds/block) + fused Avec + speed-context ----------------
__global__ __launch_bounds__(256) void k_encoder(
    const u16* __restrict__ rel, const u16* __restrict__ embW, const u16* __restrict__ embB,
    const u16* __restrict__ encF, const u16* __restrict__ encB,
    const u16* __restrict__ IT, const u16* __restrict__ IS, const u16* __restrict__ IW1H,
    const u16* __restrict__ sW, const u16* __restrict__ sB,
    const float* __restrict__ AUX,
    u16* __restrict__ ctxIn, u16* __restrict__ Avec)
{
    __shared__ __align__(16) u16 Als[16*136];
    __shared__ float pxs[16], pys[16], sps[16];
    const int t = threadIdx.x, pedbase = blockIdx.x*16;
    const int w = t>>6, lane = t&63, quad = lane>>4, l15 = lane&15;
    for (int idx = t; idx < 16*64; idx += 256){ int p = idx>>6, jj = idx&63; Als[p*136 + 64 + jj] = 0; }
    if (t < 16){
        pxs[t] = b2f(IT[7*8192 + (pedbase+t)*2 + 0]);
        pys[t] = b2f(IT[7*8192 + (pedbase+t)*2 + 1]);
        sps[t] = b2f(IS[7*4096 + pedbase + t]);
    }
    {
        int p = t>>4, e0 = (t&15)*4;
        float rx = b2f(rel[(pedbase+p)*2 + 0]);
        float ry = b2f(rel[(pedbase+p)*2 + 1]);
        for (int e = e0; e < e0+4; ++e)
            Als[p*136 + e] = f2b(rx*b2f(embW[e]) + ry*b2f(embW[64+e]) + b2f(embB[e]));
    }
    const int j = w*16 + l15;
    const float bi = b2f(encB[j]), bff = b2f(encB[64+j]), bg = b2f(encB[128+j]), bo = b2f(encB[192+j]);
    float c4[4] = {0.f,0.f,0.f,0.f};
    for (int step = 0; step < 8; ++step){
        __syncthreads();
        v4f acc[4];
        for (int q = 0; q < 4; ++q) acc[q] = (v4f){0.f,0.f,0.f,0.f};
        for (int kc = 0; kc < 4; ++kc){
            v8s a = *(const v8s*)&Als[l15*136 + kc*32 + quad*8];
            for (int q = 0; q < 4; ++q){
                int nf = q*4 + w;
                v8s b = *(const v8s*)&encF[((nf*4 + kc)*64 + lane)*8];
                acc[q] = __builtin_amdgcn_mfma_f32_16x16x32_bf16(a, b, acc[q], 0, 0, 0);
            }
        }
        __syncthreads();
        for (int r = 0; r < 4; ++r){
            float gi = sigm(acc[0][r] + bi), gf = sigm(acc[1][r] + bff);
            float gg = tanh_(acc[2][r] + bg), go = sigm(acc[3][r] + bo);
            c4[r] = gf*c4[r] + gi*gg;
            Als[(quad*4 + r)*136 + 64 + j] = f2b(go*tanh_(c4[r]));
        }
        if (step < 7){
            int p = t>>4, e0 = (t&15)*4;
            float rx = b2f(rel[(step+1)*8192 + (pedbase+p)*2 + 0]);
            float ry = b2f(rel[(step+1)*8192 + (pedbase+p)*2 + 1]);
            for (int e = e0; e < e0+4; ++e)
                Als[p*136 + e] = f2b(rx*b2f(embW[e]) + ry*b2f(embW[64+e]) + b2f(embB[e]));
        }
    }
    __syncthreads();
    for (int idx = t; idx < 1024; idx += 256){
        int p = idx>>6, e = idx&63;
        ctxIn[(size_t)(pedbase+p)*1152 + e] = Als[p*136 + 64 + e];
    }
    {
        const int c0 = (t&127)*4, pg = (t>>7)*8;
        float4 acc[8];
        for (int p = 0; p < 8; ++p) acc[p] = make_float4(0.f,0.f,0.f,0.f);
        for (int e = 0; e < 64; ++e){
            ushort4 wv = *(const ushort4*)(IW1H + e*512 + c0);
            float w0 = b2f(wv.x), w1 = b2f(wv.y), w2 = b2f(wv.z), w3 = b2f(wv.w);
            for (int p = 0; p < 8; ++p){
                float h = b2f(Als[(pg+p)*136 + 64 + e]);
                acc[p].x += h*w0; acc[p].y += h*w1; acc[p].z += h*w2; acc[p].w += h*w3;
            }
        }
        float4 m0 = *(const float4*)(AUX + c0),        m1 = *(const float4*)(AUX + 512 + c0);
        float4 qv = *(const float4*)(AUX + 1024 + c0), cv = *(const float4*)(AUX + 1536 + c0);
        float4 g1 = *(const float4*)(AUX + 2048 + c0), bb = *(const float4*)(AUX + 2560 + c0);
        for (int p = 0; p < 8; ++p){
            float px = pxs[pg+p], py = pys[pg+p], sp = sps[pg+p];
            ushort4 o;
            o.x = f2b(g1.x*(px*m0.x + py*m1.x + sp*qv.x + cv.x + acc[p].x) + bb.x);
            o.y = f2b(g1.y*(px*m0.y + py*m1.y + sp*qv.y + cv.y + acc[p].y) + bb.y);
            o.z = f2b(g1.z*(px*m0.z + py*m1.z + sp*qv.z + cv.z + acc[p].z) + bb.z);
            o.w = f2b(g1.w*(px*m0.w + py*m1.w + sp*qv.w + cv.w + acc[p].w) + bb.w);
            *(ushort4*)&Avec[(size_t)(pedbase+pg+p)*512 + c0] = o;
        }
    }
    {
        int s = t & 63;
        for (int rep = 0; rep < 4; ++rep){
            int p = (t>>6)*4 + rep;
            int nid = pedbase + p;
            float a = b2f(sB[s]);
            for (int tt = 0; tt < 8; ++tt) a += b2f(IS[tt*4096 + nid]) * b2f(sW[tt*64 + s]);
            ctxIn[(size_t)nid*1152 + 1088 + s] = f2b(sigm(a));
        }
    }
}

// ---------------- pool GEMM v6: A-frags in REGISTERS, double-buffered B, 3 blocks/CU ----------------
// M=64 (2 peds x 32 j): wave w owns rows w*16..w*16+15 (A in regs, 64 VGPR);
// B: 2x16KB LDS ping-pong via global_load_lds; one barrier/iteration.
__global__ __launch_bounds__(256, 3) void k_pool(
    const u16* __restrict__ Avec, const u16* __restrict__ W2T,
    const u16* __restrict__ IT, const float* __restrict__ AUX,
    u16* __restrict__ ctxIn)
{
    __shared__ __align__(16) u16 Bls[2][128*64];
    __shared__ float red[4][128];
    const int t = threadIdx.x;
    const int g = blockIdx.x >> 4, ip = blockIdx.x & 15;
    const int w = t>>6, lane = t&63, quad = lane>>4, l15 = lane&15;
    const int arowi = w*16 + l15;        // A-operand row for this lane
    const int pd = w >> 1;               // ped 0 (waves 0,1) / ped 1 (waves 2,3)
    const float px = b2f(IT[7*8192 + (g*32 + ip*2 + pd)*2 + 0]);
    const float py = b2f(IT[7*8192 + (g*32 + ip*2 + pd)*2 + 1]);
    const float* M0G = AUX + 3072;
    const float* M1G = AUX + 3584;
    // build A fragments in registers: afr[ch*2+kc] = relu(A[row] - pos.M) at k = ch*64+kc*32+quad*8
    v8s afr[16];
    {
        const u16* arow = Avec + (size_t)(g*32 + (arowi & 31))*512;
        const float npx = -px, npy = -py;
        #pragma unroll
        for (int ch = 0; ch < 8; ++ch){
            #pragma unroll
            for (int kc = 0; kc < 2; ++kc){
                const int k0 = ch*64 + kc*32 + quad*8;
                union { v8s v; u16 u[8]; } av; av.v = *(const v8s*)(arow + k0);
                float4 m00 = *(const float4*)(M0G + k0), m01 = *(const float4*)(M0G + k0 + 4);
                float4 m10 = *(const float4*)(M1G + k0), m11 = *(const float4*)(M1G + k0 + 4);
                float m0a[8] = {m00.x,m00.y,m00.z,m00.w,m01.x,m01.y,m01.z,m01.w};
                float m1a[8] = {m10.x,m10.y,m10.z,m10.w,m11.x,m11.y,m11.z,m11.w};
                union { v8s v; u16 u[8]; } pk;
                #pragma unroll
                for (int i = 0; i < 8; ++i){
                    float v = __builtin_fmaf(npy, m1a[i], __builtin_fmaf(npx, m0a[i], b2f(av.u[i])));
                    pk.u[i] = f2b_hu(fmaxf(v, 0.f));
                }
                afr[ch*2+kc] = pk.v;
            }
        }
    }
    // B staging: lane covers col w*8+(lane>>3) (+it2*32), granule (lane&7)^(lane>>3) [XOR slot]
    const u16* bsrc = W2T + (size_t)(w*8 + (lane>>3))*512 + (size_t)((lane&7)^(lane>>3))*8;
    u16* bd[2] = { &Bls[0][w*512], &Bls[1][w*512] };
    #pragma unroll
    for (int it2 = 0; it2 < 4; ++it2)          // prologue: stage tile 0 into buf 0
        g2lds16(bsrc + it2*16384, bd[0] + it2*2048);
    const float* S2 = AUX + 4096;
    const float* B2 = AUX + 5120;
    for (int ntile = 0; ntile < 8; ++ntile){
        v4f acc[8];
        #pragma unroll
        for (int nf = 0; nf < 8; ++nf) acc[nf] = (v4f){0.f,0.f,0.f,0.f};
        for (int ch = 0; ch < 8; ++ch){
            const int it = ntile*8 + ch;
            __syncthreads();                    // drains buf[it&1] loads (issued 1 iter ago)
            if (it < 63){
                const int nxt = it + 1;
                const u16* s = bsrc + (size_t)(nxt>>3)*65536 + (size_t)(nxt&7)*64;
                u16* d = bd[nxt & 1];
                #pragma unroll
                for (int it2 = 0; it2 < 4; ++it2)
                    g2lds16(s + it2*16384, d + it2*2048);
            }
            const u16* bb = &Bls[it & 1][0];
            #pragma unroll
            for (int kc = 0; kc < 2; ++kc){
                const v8s af = afr[ch*2 + kc];
                const int sl = ((kc*4 + quad) ^ (l15 & 7))*8;
                #pragma unroll
                for (int nf = 0; nf < 8; ++nf){
                    v8s bf = *(const v8s*)&bb[(nf*16 + l15)*64 + sl];
                    acc[nf] = __builtin_amdgcn_mfma_f32_16x16x32_bf16(af, bf, acc[nf], 0, 0, 0);
                }
            }
        }
        // epilogue: bn2+relu + max over rows (in-lane r, cross-quad shfl, cross-wave LDS)
        #pragma unroll
        for (int nf = 0; nf < 8; ++nf){
            int n = ntile*128 + nf*16 + l15;
            float s = S2[n], bo = B2[n];
            float m = 0.f;
            for (int r = 0; r < 4; ++r) m = fmaxf(m, fmaxf(s*acc[nf][r] + bo, 0.f));
            m = fmaxf(m, __shfl_xor(m, 16));
            m = fmaxf(m, __shfl_xor(m, 32));
            if (quad == 0) red[w][nf*16 + l15] = m;
        }
        __syncthreads();
        {
            int c = t & 127, pd2 = t >> 7;
            float m = fmaxf(red[pd2*2][c], red[pd2*2 + 1][c]);
            ctxIn[(size_t)(g*32 + ip*2 + pd2)*1152 + 64 + ntile*128 + c] = f2b(m);
        }
    }
}

// ---------------- generic MFMA GEMM, M-tile = MF*32: out = relu(S[n]*A@BT' + Bb[n]) ----------------
template<int MF>
__global__ __launch_bounds__(256) void k_gemm_bt(
    const u16* __restrict__ A, int lda, const u16* __restrict__ BT,
    const float* __restrict__ S, const float* __restrict__ Bb,
    u16* __restrict__ out, int ldo, int K, int validN,
    const u16* __restrict__ noisep)
{
    __shared__ __align__(16) u16 Als[MF*32*72];
    __shared__ __align__(16) u16 Bls[128*72];
    const int t = threadIdx.x;
    const int m0 = blockIdx.x*(MF*32), n0 = blockIdx.y*128;
    const int w = t>>6, lane = t&63, quad = lane>>4, l15 = lane&15;
    const int rw = w>>1, cw = w&1;
    v4f acc[MF][4];
    for (int mf = 0; mf < MF; ++mf) for (int nf = 0; nf < 4; ++nf) acc[mf][nf] = (v4f){0.f,0.f,0.f,0.f};
    const int nch = K >> 6;
    for (int ch = 0; ch < nch; ++ch){
        const int k0 = ch*64;
        __syncthreads();
        if (MF == 4){
            const int srow = t>>1, sh = t&1;
            const u16* srcA = A + (size_t)(m0+srow)*lda + k0 + sh*32;
            u16* dstA = &Als[srow*72 + sh*32];
            ((v8s*)dstA)[0] = ((const v8s*)srcA)[0];
            ((v8s*)dstA)[1] = ((const v8s*)srcA)[1];
            ((v8s*)dstA)[2] = ((const v8s*)srcA)[2];
            ((v8s*)dstA)[3] = ((const v8s*)srcA)[3];
        } else {
            const int srow = t>>2, sh = t&3;
            const u16* srcA = A + (size_t)(m0+srow)*lda + k0 + sh*16;
            u16* dstA = &Als[srow*72 + sh*16];
            ((v8s*)dstA)[0] = ((const v8s*)srcA)[0];
            ((v8s*)dstA)[1] = ((const v8s*)srcA)[1];
        }
        {
            const int srow = t>>1, sh = t&1;
            const u16* srcB = BT + (size_t)(n0+srow)*K + k0 + sh*32;
            u16* dstB = &Bls[srow*72 + sh*32];
            ((v8s*)dstB)[0] = ((const v8s*)srcB)[0];
            ((v8s*)dstB)[1] = ((const v8s*)srcB)[1];
            ((v8s*)dstB)[2] = ((const v8s*)srcB)[2];
            ((v8s*)dstB)[3] = ((const v8s*)srcB)[3];
        }
        __syncthreads();
        for (int kc = 0; kc < 2; ++kc){
            v8s af[MF], bf[4];
            for (int mf = 0; mf < MF; ++mf) af[mf] = *(const v8s*)&Als[(rw*(MF*16) + mf*16 + l15)*72 + kc*32 + quad*8];
            for (int nf = 0; nf < 4; ++nf) bf[nf] = *(const v8s*)&Bls[(cw*64 + nf*16 + l15)*72 + kc*32 + quad*8];
            for (int mf = 0; mf < MF; ++mf)
                for (int nf = 0; nf < 4; ++nf)
                    acc[mf][nf] = __builtin_amdgcn_mfma_f32_16x16x32_bf16(af[mf], bf[nf], acc[mf][nf], 0, 0, 0);
        }
    }
    for (int nf = 0; nf < 4; ++nf){
        int n = n0 + cw*64 + nf*16 + l15;
        bool okn = (n < validN);
        float s = okn ? S[n] : 0.f, bb = okn ? Bb[n] : 0.f;
        bool okz = (!okn) && (noisep != nullptr) && (n < 128);
        for (int mf = 0; mf < MF; ++mf){
            int m = m0 + rw*(MF*16) + mf*16 + quad*4;
            for (int r = 0; r < 4; ++r){
                float v = fmaxf(s*acc[mf][nf][r] + bb, 0.f);
                if (okn) out[(size_t)(m+r)*ldo + n] = f2b(v);
                else if (okz) out[(size_t)(m+r)*ldo + n] = noisep[(size_t)(m+r)*8 + (n - 120)];
            }
        }
    }
}

// ---------------- decoder LSTM rollout ----------------
__global__ __launch_bounds__(256) void k_decoder(
    const u16* __restrict__ decH0, const u16* __restrict__ decF, const u16* __restrict__ decB,
    const u16* __restrict__ dembW, const u16* __restrict__ dembB,
    const u16* __restrict__ h2pW, const u16* __restrict__ h2pB,
    const u16* __restrict__ obs_rel, const u16* __restrict__ obs_speed,
    const int* __restrict__ flag, void* __restrict__ outp)
{
    __shared__ __align__(16) u16 Als[16*200];
    __shared__ float rps[16][2];
    __shared__ float sps[16];
    __shared__ float h2ps[256];
    const int t = threadIdx.x, pedbase = blockIdx.x*16;
    const int w = t>>6, lane = t&63, quad = lane>>4, l15 = lane&15;
    const int isf = *flag;
    for (int idx = t; idx < 2048; idx += 256){
        int p = idx>>7, jj = idx&127;
        Als[p*200 + 64 + jj] = decH0[(pedbase+p)*128 + jj];
    }
    h2ps[t] = b2f(h2pW[t]);
    if (t < 16) sps[t] = b2f(obs_speed[7*4096 + pedbase + t]);
    if (t < 32){ int p = t>>1, cmp = t&1; rps[p][cmp] = b2f(obs_rel[7*8192 + (pedbase+p)*2 + cmp]); }
    __syncthreads();
    {
        int p = t>>4, e0 = (t&15)*4;
        for (int e = e0; e < e0+4; ++e){
            float v = rps[p][0]*b2f(dembW[e]) + rps[p][1]*b2f(dembW[64+e]) + sps[p]*b2f(dembW[128+e]) + b2f(dembB[e]);
            Als[p*200 + e] = f2b(v);
        }
    }
    float bI[2], bF[2], bG[2], bO[2];
    for (int nfl = 0; nfl < 2; ++nfl){
        int j = w*32 + nfl*16 + l15;
        bI[nfl] = b2f(decB[j]); bF[nfl] = b2f(decB[128+j]);
        bG[nfl] = b2f(decB[256+j]); bO[nfl] = b2f(decB[384+j]);
    }
    float c8[2][4] = {{0.f,0.f,0.f,0.f},{0.f,0.f,0.f,0.f}};
    for (int s = 0; s < 12; ++s){
        __syncthreads();
        v4f acc[4][2];
        for (int q = 0; q < 4; ++q) for (int nfl = 0; nfl < 2; ++nfl) acc[q][nfl] = (v4f){0.f,0.f,0.f,0.f};
        for (int kc = 0; kc < 6; ++kc){
            v8s a = *(const v8s*)&Als[l15*200 + kc*32 + quad*8];
            for (int q = 0; q < 4; ++q){
                for (int nfl = 0; nfl < 2; ++nfl){
                    int nf = q*8 + w*2 + nfl;
                    v8s b = *(const v8s*)&decF[((nf*6 + kc)*64 + lane)*8];
                    acc[q][nfl] = __builtin_amdgcn_mfma_f32_16x16x32_bf16(a, b, acc[q][nfl], 0, 0, 0);
                }
            }
        }
        __syncthreads();
        for (int nfl = 0; nfl < 2; ++nfl){
            int j = w*32 + nfl*16 + l15;
            for (int r = 0; r < 4; ++r){
                float gi = sigm(acc[0][nfl][r] + bI[nfl]), gf = sigm(acc[1][nfl][r] + bF[nfl]);
                float gg = tanh_(acc[2][nfl][r] + bG[nfl]), go = sigm(acc[3][nfl][r] + bO[nfl]);
                c8[nfl][r] = gf*c8[nfl][r] + gi*gg;
                Als[(quad*4 + r)*200 + 64 + j] = f2b(go*tanh_(c8[nfl][r]));
            }
        }
        __syncthreads();
        {
            int p = t>>4, cmp = (t>>3)&1, part = t&7;
            float rp = 0.f;
            int j0 = part*16;
            for (int jj = j0; jj < j0+16; ++jj)
                rp += b2f(Als[p*200 + 64 + jj]) * h2ps[jj*2 + cmp];
            rp += __shfl_xor(rp, 1);
            rp += __shfl_xor(rp, 2);
            rp += __shfl_xor(rp, 4);
            if (part == 0){
                rp += b2f(h2pB[cmp]);
                int oi = s*8192 + (pedbase+p)*2 + cmp;
                if (isf) ((float*)outp)[oi] = rp;
                else     ((u16*)outp)[oi]   = f2b(rp);
                rps[p][cmp] = rp;
            }
        }
        __syncthreads();
        {
            int p = t>>4, e0 = (t&15)*4;
            for (int e = e0; e < e0+4; ++e){
                float v = rps[p][0]*b2f(dembW[e]) + rps[p][1]*b2f(dembW[64+e]) + sps[p]*b2f(dembW[128+e]) + b2f(dembB[e]);
                Als[p*200 + e] = f2b(v);
            }
        }
    }
}

extern "C" void kernel_launch(void* const* d_in, const int* in_sizes, int n_in,
                              void* d_out, int out_size, void* d_ws, size_t ws_size,
                              hipStream_t stream)
{
    (void)in_sizes; (void)n_in; (void)out_size;
    const void* obs_traj  = d_in[0];
    const void* obs_rel   = d_in[1];
    const void* obs_speed = d_in[2];
    const void* noise     = d_in[3];
    const void* enc_emb_W = d_in[4];
    const void* enc_emb_b = d_in[5];
    const void* enc_Wih   = d_in[6];
    const void* enc_Whh   = d_in[7];
    const void* enc_b     = d_in[8];
    const void* pool_sp_W = d_in[9];
    const void* pool_sp_b = d_in[10];
    const void* pool_spd_W= d_in[11];
    const void* pool_spd_b= d_in[12];
    const void* pool_l1_W = d_in[13];
    const void* pool_l1_b = d_in[14];
    const void* pool_bn1_g= d_in[15];
    const void* pool_bn1_b= d_in[16];
    const void* pool_l2_W = d_in[17];
    const void* pool_l2_b = d_in[18];
    const void* pool_bn2_g= d_in[19];
    const void* pool_bn2_b= d_in[20];
    const void* spd_emb_W = d_in[21];
    const void* spd_emb_b = d_in[22];
    const void* ctx_l1_W  = d_in[23];
    const void* ctx_l1_b  = d_in[24];
    const void* ctx_bn1_g = d_in[25];
    const void* ctx_bn1_b = d_in[26];
    const void* ctx_l2_W  = d_in[27];
    const void* ctx_l2_b  = d_in[28];
    const void* ctx_bn2_g = d_in[29];
    const void* ctx_bn2_b = d_in[30];
    const void* dec_emb_W = d_in[31];
    const void* dec_emb_b = d_in[32];
    const void* dec_Wih   = d_in[33];
    const void* dec_Whh   = d_in[34];
    const void* dec_b     = d_in[35];
    const void* h2p_W     = d_in[36];
    const void* h2p_b     = d_in[37];

    char* ws = (char*)d_ws;
    int*   flag  = (int*)  (ws + FLAG_OFF);
    float* AUX   = (float*)(ws + AUX_OFF);
    u16*   encF  = (u16*)  (ws + ENCF_OFF);
    u16*   decF  = (u16*)  (ws + DECF_OFF);
    u16*   cW2T  = (u16*)  (ws + CW2T_OFF);
    u16*   W2T   = (u16*)  (ws + W2T_OFF);
    u16*   decH  = (u16*)  (ws + DECH_OFF);
    u16*   cW1T  = (u16*)  (ws + CW1T_OFF);
    u16*   IT    = (u16*)  (ws + IT_OFF);
    u16*   IR    = (u16*)  (ws + IR_OFF);
    u16*   IS    = (u16*)  (ws + IS_OFF);
    u16*   INZ   = (u16*)  (ws + INZ_OFF);
    u16*   IW1H  = (u16*)  (ws + IW1H_OFF);
    u16*   SM    = (u16*)  (ws + SM_OFF);
    u16*   ctxIn = (u16*)  (ws + CTX_OFF);
    u16*   Avec  = (u16*)  (ws + AV_OFF);
    u16*   c1    = (u16*)  (ws + AV_OFF);   // overlays Avec (dead after k_pool)
    const bool big = (ws_size >= (size_t)BIG_NEED);

    k_prep<<<dim3(1876), dim3(256), 0, stream>>>(
        obs_traj, obs_rel, obs_speed, noise,
        enc_emb_W, enc_emb_b, enc_Wih, enc_Whh, enc_b,
        pool_sp_W, pool_sp_b, pool_spd_W, pool_spd_b,
        pool_l1_W, pool_l1_b, pool_bn1_g, pool_bn1_b,
        pool_l2_W, pool_l2_b, pool_bn2_g, pool_bn2_b,
        spd_emb_W, spd_emb_b,
        ctx_l1_W, ctx_l1_b, ctx_bn1_g, ctx_bn1_b,
        ctx_l2_W, ctx_l2_b, ctx_bn2_g, ctx_bn2_b,
        dec_emb_W, dec_emb_b, dec_Wih, dec_Whh, dec_b,
        h2p_W, h2p_b,
        flag, AUX, IT, IR, IS, INZ, IW1H, SM,
        W2T, cW1T, cW2T, encF, decF);
    k_encoder<<<dim3(256), dim3(256), 0, stream>>>(
        IR, SM + SM_EEW, SM + SM_EEB, encF, SM + SM_ENB,
        IT, IS, IW1H, SM + SM_SEW, SM + SM_SEB, AUX, ctxIn, Avec);
    k_pool<<<dim3(2048), dim3(256), 0, stream>>>(Avec, W2T, IT, AUX, ctxIn);
    if (big){
        k_gemm_bt<4><<<dim3(32, 8), dim3(256), 0, stream>>>(
            ctxIn, 1152, cW1T, AUX + 6144, AUX + 7168, c1, 1024, 1152, 1024, (const u16*)nullptr);
        k_gemm_bt<2><<<dim3(64, 1), dim3(256), 0, stream>>>(
            c1, 1024, cW2T, AUX + 8192, AUX + 8320, decH, 128, 1024, 120, INZ);
    } else {
        k_gemm_bt<4><<<dim3(16, 8), dim3(256), 0, stream>>>(
            ctxIn, 1152, cW1T, AUX + 6144, AUX + 7168, c1, 1024, 1152, 1024, (const u16*)nullptr);
        k_gemm_bt<2><<<dim3(32, 1), dim3(256), 0, stream>>>(
            c1, 1024, cW2T, AUX + 8192, AUX + 8320, decH, 128, 1024, 120, INZ);
        k_gemm_bt<4><<<dim3(16, 8), dim3(256), 0, stream>>>(
            ctxIn + (size_t)2048*1152, 1152, cW1T, AUX + 6144, AUX + 7168, c1, 1024, 1152, 1024, (const u16*)nullptr);
        k_gemm_bt<2><<<dim3(32, 1), dim3(256), 0, stream>>>(
            c1, 1024, cW2T, AUX + 8192, AUX + 8320, decH + (size_t)2048*128, 128, 1024, 120, INZ + (size_t)2048*8);
    }
    k_decoder<<<dim3(256), dim3(256), 0, stream>>>(
        decH, decF, SM + SM_DNB, SM + SM_DEW, SM + SM_DEB,
        SM + SM_H2W, SM + SM_H2B, IR, IS, flag, d_out);
}

// Round 9
// 492.581 us; speedup vs baseline: 1.0264x; 1.0264x over previous
//
#include <hip/hip_runtime.h>

typedef __attribute__((ext_vector_type(8))) short v8s;
typedef __attribute__((ext_vector_type(4))) float v4f;
typedef unsigned short u16;

#define DINL static __device__ __forceinline__

DINL float b2f(u16 u){ union { unsigned uu; float ff; } x; x.uu = ((unsigned)u)<<16; return x.ff; }
DINL u16 f2b(float f){ union { float ff; unsigned uu; } x; x.ff = f; unsigned r = x.uu + 0x7FFFu + ((x.uu>>16)&1u); return (u16)(r>>16); }
DINL u16 f2b_hu(float f){ union { float ff; unsigned uu; } x; x.ff = f; return (u16)((x.uu + 0x8000u)>>16); }
DINL float sigm(float x){ return 1.0f/(1.0f+__expf(-x)); }
DINL float tanh_(float x){ return 2.0f/(1.0f+__expf(-2.0f*x)) - 1.0f; }
DINL float ld(const void* p, int i, int isf){
    return isf ? ((const float*)p)[i] : b2f(((const u16*)p)[i]);
}
DINL void g2lds16(const u16* g, u16* l){
    __builtin_amdgcn_global_load_lds(
        (const __attribute__((address_space(1))) unsigned int*)g,
        (__attribute__((address_space(3))) unsigned int*)l, 16, 0, 0);
}
DINL int detect_isf(const void* obs_speed){
    const u16* p = (const u16*)obs_speed;
    int f = 0;
    for (int i = 0; i < 16; ++i){
        u16 v = p[2*i];
        if ((v & 0x8000u) || v > 0x3F80u) f = 1;
    }
    return f;
}

// ---- workspace byte offsets ----
#define FLAG_OFF 0x000000
#define AUX_OFF  0x000100
#define ENCF_OFF 0x010000
#define DECF_OFF 0x020000
#define CW2T_OFF 0x050000
#define W2T_OFF  0x090000   // dead after k_pool; decH overlays
#define DECH_OFF 0x090000
#define CW1T_OFF 0x190000
#define IT_OFF   0x3D0000
#define IR_OFF   0x3F0000
#define IS_OFF   0x410000
#define INZ_OFF  0x420000
#define IW1H_OFF 0x430000
#define SM_OFF   0x440000
#define CTX_OFF  0x450000   // ctx_in 4096x1152 bf16
#define AV_OFF   0xD50000   // Avec bf16 (dead after k_pool); c1 overlays
#define BIG_NEED 0x1550000  // AV_OFF + 8MB single-pass c1

#define SM_EEW 0
#define SM_EEB 128
#define SM_ENB 192
#define SM_DEW 448
#define SM_DEB 640
#define SM_DNB 704
#define SM_H2W 1216
#define SM_H2B 1472
#define SM_SEW 1536
#define SM_SEB 2048

// ---------------- unified prep kernel ----------------
DINL void trans_tile(const void* in, u16* out, int K, int N, int isf,
                     int bx, int by, int t, float tile[64][65])
{
    const int nbase = bx*64, kbase = by*64;
    const int c = t & 63, r0 = (t >> 6)*16;
    for (int rep = 0; rep < 16; ++rep){
        int r = r0 + rep;
        int n = nbase + c;
        float v = 0.f;
        if (n < N) v = ld(in, (kbase + r)*N + n, isf);
        tile[r][c] = v;
    }
    __syncthreads();
    for (int rep = 0; rep < 16; ++rep){
        int r = r0 + rep;
        out[(size_t)(nbase + r)*K + kbase + c] = f2b(tile[c][r]);
    }
}

__global__ __launch_bounds__(256) void k_prep(
    const void* obs_traj, const void* obs_rel, const void* obs_speed, const void* noise,
    const void* eeW, const void* eeB, const void* enc_Wih, const void* enc_Whh, const void* encB,
    const void* spW, const void* spB, const void* spdW, const void* spdB,
    const void* pool_l1_W, const void* l1B, const void* bn1g, const void* bn1b,
    const void* pool_l2_W, const void* l2b, const void* bn2g, const void* bn2b,
    const void* seW, const void* seB,
    const void* ctx_l1_W, const void* c1b, const void* cbn1g, const void* cbn1b,
    const void* ctx_l2_W, const void* c2b, const void* cbn2g, const void* cbn2b,
    const void* deW, const void* deB, const void* dec_Wih, const void* dec_Whh, const void* decB,
    const void* h2W, const void* h2B,
    int* flag, float* AUX,
    u16* IT, u16* IR, u16* IS, u16* INZ, u16* IW1H, u16* SM,
    u16* W2T, u16* cW1T, u16* cW2T, u16* encF, u16* decF)
{
    __shared__ float tile[64][65];
    __shared__ int sisf;
    const int t = threadIdx.x;
    if (t == 0){
        int f = detect_isf(obs_speed);
        sisf = f;
        if (blockIdx.x == 0) *flag = f;
    }
    __syncthreads();
    const int isf = sisf;
    int bid = blockIdx.x;
    if (bid < 905){
        int idx = bid*256 + t;
        if (idx < 65536){ IT[idx] = f2b(ld(obs_traj, idx, isf)); return; }
        idx -= 65536;
        if (idx < 65536){ IR[idx] = f2b(ld(obs_rel, idx, isf)); return; }
        idx -= 65536;
        if (idx < 32768){ IS[idx] = f2b(ld(obs_speed, idx, isf)); return; }
        idx -= 32768;
        if (idx < 32768){ INZ[idx] = f2b(ld(noise, idx, isf)); return; }
        idx -= 32768;
        if (idx < 32768){ IW1H[idx] = f2b(ld(pool_l1_W, idx + 32768, isf)); return; }
        idx -= 32768;
        if (idx < 128){ SM[SM_EEW + idx] = f2b(ld(eeW, idx, isf)); return; }
        idx -= 128;
        if (idx < 64){ SM[SM_EEB + idx] = f2b(ld(eeB, idx, isf)); return; }
        idx -= 64;
        if (idx < 256){ SM[SM_ENB + idx] = f2b(ld(encB, idx, isf)); return; }
        idx -= 256;
        if (idx < 192){ SM[SM_DEW + idx] = f2b(ld(deW, idx, isf)); return; }
        idx -= 192;
        if (idx < 64){ SM[SM_DEB + idx] = f2b(ld(deB, idx, isf)); return; }
        idx -= 64;
        if (idx < 512){ SM[SM_DNB + idx] = f2b(ld(decB, idx, isf)); return; }
        idx -= 512;
        if (idx < 256){ SM[SM_H2W + idx] = f2b(ld(h2W, idx, isf)); return; }
        idx -= 256;
        if (idx < 2){ SM[SM_H2B + idx] = f2b(ld(h2B, idx, isf)); return; }
        idx -= 2;
        if (idx < 512){ SM[SM_SEW + idx] = f2b(ld(seW, idx, isf)); return; }
        idx -= 512;
        if (idx < 64){ SM[SM_SEB + idx] = f2b(ld(seB, idx, isf)); return; }
        return;
    }
    bid -= 905;
    if (bid < 512){
        int idx = bid*256 + t;
        if (idx < 32768){
            int jj = idx&7, lane = (idx>>3)&63, kcnf = idx>>9;
            int kc = kcnf&3, nf = kcnf>>2;
            int k = kc*32 + (lane>>4)*8 + jj, n = nf*16 + (lane&15);
            encF[idx] = (k < 64) ? f2b(ld(enc_Wih, k*256+n, isf)) : f2b(ld(enc_Whh, (k-64)*256+n, isf));
        } else {
            idx -= 32768;
            int jj = idx&7, lane = (idx>>3)&63, kcnf = idx>>9;
            int kc = kcnf % 6, nf = kcnf / 6;
            int k = kc*32 + (lane>>4)*8 + jj, n = nf*16 + (lane&15);
            decF[idx] = (k < 64) ? f2b(ld(dec_Wih, k*512+n, isf)) : f2b(ld(dec_Whh, (k-64)*512+n, isf));
        }
        return;
    }
    bid -= 512;
    if (bid < 128){ trans_tile(pool_l2_W, W2T, 512, 1024, isf, bid & 15, bid >> 4, t, tile); return; }
    bid -= 128;
    if (bid < 288){ trans_tile(ctx_l1_W, cW1T, 1152, 1024, isf, bid & 15, bid >> 4, t, tile); return; }
    bid -= 288;
    if (bid < 32){ trans_tile(ctx_l2_W, cW2T, 1024, 120, isf, bid & 1, bid >> 1, t, tile); return; }
    bid -= 32;
    {
        int idx = bid*256 + t;
        if (idx < 512){
            int c = idx;
            float m0 = 0.f, m1 = 0.f, qv = 0.f, cv = 0.f;
            for (int e = 0; e < 64; ++e){
                float w1a = ld(pool_l1_W, e*512 + c, isf);
                m0 += ld(spW, e, isf)*w1a;
                m1 += ld(spW, 64+e, isf)*w1a;
                cv += ld(spB, e, isf)*w1a;
                float w1c = ld(pool_l1_W, (128+e)*512 + c, isf);
                qv += ld(spdW, e, isf)*w1c;
                cv += ld(spdB, e, isf)*w1c;
            }
            cv += ld(l1B, c, isf);
            float g1 = ld(bn1g, c, isf), bb1 = ld(bn1b, c, isf);
            AUX[c] = m0; AUX[512+c] = m1; AUX[1024+c] = qv; AUX[1536+c] = cv;
            AUX[2048+c] = g1; AUX[2560+c] = bb1;
            AUX[3072+c] = g1*m0; AUX[3584+c] = g1*m1;
            return;
        }
        idx -= 512;
        if (idx < 1024){
            float g = ld(bn2g, idx, isf);
            AUX[4096+idx] = g; AUX[5120+idx] = ld(l2b, idx, isf)*g + ld(bn2b, idx, isf);
            return;
        }
        idx -= 1024;
        if (idx < 1024){
            float g = ld(cbn1g, idx, isf);
            AUX[6144+idx] = g; AUX[7168+idx] = ld(c1b, idx, isf)*g + ld(cbn1b, idx, isf);
            return;
        }
        idx -= 1024;
        if (idx < 128){
            int c = idx;
            float g  = (c < 120) ? ld(cbn2g, c, isf) : 1.f;
            float bb = (c < 120) ? (ld(c2b, c, isf)*g + ld(cbn2b, c, isf)) : 0.f;
            AUX[8192+c] = g; AUX[8320+c] = bb;
        }
    }
}

// ---------------- encoder LSTM (16 peds/block) + fused Avec + speed-context ----------------
__global__ __launch_bounds__(256) void k_encoder(
    const u16* __restrict__ rel, const u16* __restrict__ embW, const u16* __restrict__ embB,
    const u16* __restrict__ encF, const u16* __restrict__ encB,
    const u16* __restrict__ IT, const u16* __restrict__ IS, const u16* __restrict__ IW1H,
    const u16* __restrict__ sW, const u16* __restrict__ sB,
    const float* __restrict__ AUX,
    u16* __restrict__ ctxIn, u16* __restrict__ Avec)
{
    __shared__ __align__(16) u16 Als[16*136];
    __shared__ float pxs[16], pys[16], sps[16];
    const int t = threadIdx.x, pedbase = blockIdx.x*16;
    const int w = t>>6, lane = t&63, quad = lane>>4, l15 = lane&15;
    for (int idx = t; idx < 16*64; idx += 256){ int p = idx>>6, jj = idx&63; Als[p*136 + 64 + jj] = 0; }
    if (t < 16){
        pxs[t] = b2f(IT[7*8192 + (pedbase+t)*2 + 0]);
        pys[t] = b2f(IT[7*8192 + (pedbase+t)*2 + 1]);
        sps[t] = b2f(IS[7*4096 + pedbase + t]);
    }
    {
        int p = t>>4, e0 = (t&15)*4;
        float rx = b2f(rel[(pedbase+p)*2 + 0]);
        float ry = b2f(rel[(pedbase+p)*2 + 1]);
        for (int e = e0; e < e0+4; ++e)
            Als[p*136 + e] = f2b(rx*b2f(embW[e]) + ry*b2f(embW[64+e]) + b2f(embB[e]));
    }
    const int j = w*16 + l15;
    const float bi = b2f(encB[j]), bff = b2f(encB[64+j]), bg = b2f(encB[128+j]), bo = b2f(encB[192+j]);
    float c4[4] = {0.f,0.f,0.f,0.f};
    for (int step = 0; step < 8; ++step){
        __syncthreads();
        v4f acc[4];
        for (int q = 0; q < 4; ++q) acc[q] = (v4f){0.f,0.f,0.f,0.f};
        for (int kc = 0; kc < 4; ++kc){
            v8s a = *(const v8s*)&Als[l15*136 + kc*32 + quad*8];
            for (int q = 0; q < 4; ++q){
                int nf = q*4 + w;
                v8s b = *(const v8s*)&encF[((nf*4 + kc)*64 + lane)*8];
                acc[q] = __builtin_amdgcn_mfma_f32_16x16x32_bf16(a, b, acc[q], 0, 0, 0);
            }
        }
        __syncthreads();
        for (int r = 0; r < 4; ++r){
            float gi = sigm(acc[0][r] + bi), gf = sigm(acc[1][r] + bff);
            float gg = tanh_(acc[2][r] + bg), go = sigm(acc[3][r] + bo);
            c4[r] = gf*c4[r] + gi*gg;
            Als[(quad*4 + r)*136 + 64 + j] = f2b(go*tanh_(c4[r]));
        }
        if (step < 7){
            int p = t>>4, e0 = (t&15)*4;
            float rx = b2f(rel[(step+1)*8192 + (pedbase+p)*2 + 0]);
            float ry = b2f(rel[(step+1)*8192 + (pedbase+p)*2 + 1]);
            for (int e = e0; e < e0+4; ++e)
                Als[p*136 + e] = f2b(rx*b2f(embW[e]) + ry*b2f(embW[64+e]) + b2f(embB[e]));
        }
    }
    __syncthreads();
    for (int idx = t; idx < 1024; idx += 256){
        int p = idx>>6, e = idx&63;
        ctxIn[(size_t)(pedbase+p)*1152 + e] = Als[p*136 + 64 + e];
    }
    {
        const int c0 = (t&127)*4, pg = (t>>7)*8;
        float4 acc[8];
        for (int p = 0; p < 8; ++p) acc[p] = make_float4(0.f,0.f,0.f,0.f);
        for (int e = 0; e < 64; ++e){
            ushort4 wv = *(const ushort4*)(IW1H + e*512 + c0);
            float w0 = b2f(wv.x), w1 = b2f(wv.y), w2 = b2f(wv.z), w3 = b2f(wv.w);
            for (int p = 0; p < 8; ++p){
                float h = b2f(Als[(pg+p)*136 + 64 + e]);
                acc[p].x += h*w0; acc[p].y += h*w1; acc[p].z += h*w2; acc[p].w += h*w3;
            }
        }
        float4 m0 = *(const float4*)(AUX + c0),        m1 = *(const float4*)(AUX + 512 + c0);
        float4 qv = *(const float4*)(AUX + 1024 + c0), cv = *(const float4*)(AUX + 1536 + c0);
        float4 g1 = *(const float4*)(AUX + 2048 + c0), bb = *(const float4*)(AUX + 2560 + c0);
        for (int p = 0; p < 8; ++p){
            float px = pxs[pg+p], py = pys[pg+p], sp = sps[pg+p];
            ushort4 o;
            o.x = f2b(g1.x*(px*m0.x + py*m1.x + sp*qv.x + cv.x + acc[p].x) + bb.x);
            o.y = f2b(g1.y*(px*m0.y + py*m1.y + sp*qv.y + cv.y + acc[p].y) + bb.y);
            o.z = f2b(g1.z*(px*m0.z + py*m1.z + sp*qv.z + cv.z + acc[p].z) + bb.z);
            o.w = f2b(g1.w*(px*m0.w + py*m1.w + sp*qv.w + cv.w + acc[p].w) + bb.w);
            *(ushort4*)&Avec[(size_t)(pedbase+pg+p)*512 + c0] = o;
        }
    }
    {
        int s = t & 63;
        for (int rep = 0; rep < 4; ++rep){
            int p = (t>>6)*4 + rep;
            int nid = pedbase + p;
            float a = b2f(sB[s]);
            for (int tt = 0; tt < 8; ++tt) a += b2f(IS[tt*4096 + nid]) * b2f(sW[tt*64 + s]);
            ctxIn[(size_t)nid*1152 + 1088 + s] = f2b(sigm(a));
        }
    }
}

// ---------------- pool GEMM v7: v6 with the ch-loop UNROLLED so afr[] stays in VGPRs ----------------
// M=64 (2 peds x 32 j): wave w owns rows w*16..w*16+15 (A in regs, 64 VGPR);
// B: 2x16KB LDS ping-pong via global_load_lds; one barrier/iteration.
__global__ __launch_bounds__(256, 3) void k_pool(
    const u16* __restrict__ Avec, const u16* __restrict__ W2T,
    const u16* __restrict__ IT, const float* __restrict__ AUX,
    u16* __restrict__ ctxIn)
{
    __shared__ __align__(16) u16 Bls[2][128*64];
    __shared__ float red[4][128];
    const int t = threadIdx.x;
    const int g = blockIdx.x >> 4, ip = blockIdx.x & 15;
    const int w = t>>6, lane = t&63, quad = lane>>4, l15 = lane&15;
    const int pd = w >> 1;               // ped 0 (waves 0,1) / ped 1 (waves 2,3)
    const float px = b2f(IT[7*8192 + (g*32 + ip*2 + pd)*2 + 0]);
    const float py = b2f(IT[7*8192 + (g*32 + ip*2 + pd)*2 + 1]);
    const float* M0G = AUX + 3072;
    const float* M1G = AUX + 3584;
    // build A fragments in registers: afr[ch*2+kc] = relu(A[row] - pos.M) at k = ch*64+kc*32+quad*8
    v8s afr[16];
    {
        const u16* arow = Avec + (size_t)(g*32 + l15 + (w&1)*16)*512;   // row = (w&1)*16 + l15 within ped's 32 j... 
        // NOTE: rows per wave: wave w covers rows w*16..w*16+15 of the 64-row A (j = (w*16+l15) & 31)
        arow = Avec + (size_t)(g*32 + ((w*16 + l15) & 31))*512;
        const float npx = -px, npy = -py;
        #pragma unroll
        for (int ch = 0; ch < 8; ++ch){
            #pragma unroll
            for (int kc = 0; kc < 2; ++kc){
                const int k0 = ch*64 + kc*32 + quad*8;
                union { v8s v; u16 u[8]; } av; av.v = *(const v8s*)(arow + k0);
                float4 m00 = *(const float4*)(M0G + k0), m01 = *(const float4*)(M0G + k0 + 4);
                float4 m10 = *(const float4*)(M1G + k0), m11 = *(const float4*)(M1G + k0 + 4);
                float m0a[8] = {m00.x,m00.y,m00.z,m00.w,m01.x,m01.y,m01.z,m01.w};
                float m1a[8] = {m10.x,m10.y,m10.z,m10.w,m11.x,m11.y,m11.z,m11.w};
                union { v8s v; u16 u[8]; } pk;
                #pragma unroll
                for (int i = 0; i < 8; ++i){
                    float v = __builtin_fmaf(npy, m1a[i], __builtin_fmaf(npx, m0a[i], b2f(av.u[i])));
                    pk.u[i] = f2b_hu(fmaxf(v, 0.f));
                }
                afr[ch*2+kc] = pk.v;
            }
        }
    }
    // B staging: lane covers col w*8+(lane>>3) (+it2*32), granule (lane&7)^(lane>>3) [XOR slot]
    const u16* bsrc = W2T + (size_t)(w*8 + (lane>>3))*512 + (size_t)((lane&7)^(lane>>3))*8;
    u16* bd[2] = { &Bls[0][w*512], &Bls[1][w*512] };
    #pragma unroll
    for (int it2 = 0; it2 < 4; ++it2)          // prologue: stage tile 0 into buf 0
        g2lds16(bsrc + it2*16384, bd[0] + it2*2048);
    const float* S2 = AUX + 4096;
    const float* B2 = AUX + 5120;
    for (int ntile = 0; ntile < 8; ++ntile){
        v4f acc[8];
        #pragma unroll
        for (int nf = 0; nf < 8; ++nf) acc[nf] = (v4f){0.f,0.f,0.f,0.f};
        #pragma unroll
        for (int ch = 0; ch < 8; ++ch){        // UNROLLED: afr[] indices static -> stays in VGPRs
            const int it = ntile*8 + ch;
            __syncthreads();                    // drains buf[it&1] loads (issued 1 iter ago)
            if (it < 63){
                const int nxt = it + 1;
                const u16* s = bsrc + (size_t)(nxt>>3)*65536 + (size_t)(nxt&7)*64;
                u16* d = bd[nxt & 1];
                #pragma unroll
                for (int it2 = 0; it2 < 4; ++it2)
                    g2lds16(s + it2*16384, d + it2*2048);
            }
            const u16* bb = &Bls[it & 1][0];
            #pragma unroll
            for (int kc = 0; kc < 2; ++kc){
                const v8s af = afr[ch*2 + kc];
                const int sl = ((kc*4 + quad) ^ (l15 & 7))*8;
                #pragma unroll
                for (int nf = 0; nf < 8; ++nf){
                    v8s bf = *(const v8s*)&bb[(nf*16 + l15)*64 + sl];
                    acc[nf] = __builtin_amdgcn_mfma_f32_16x16x32_bf16(af, bf, acc[nf], 0, 0, 0);
                }
            }
        }
        // epilogue: bn2+relu + max over rows (in-lane r, cross-quad shfl, cross-wave LDS)
        #pragma unroll
        for (int nf = 0; nf < 8; ++nf){
            int n = ntile*128 + nf*16 + l15;
            float s = S2[n], bo = B2[n];
            float m = 0.f;
            for (int r = 0; r < 4; ++r) m = fmaxf(m, fmaxf(s*acc[nf][r] + bo, 0.f));
            m = fmaxf(m, __shfl_xor(m, 16));
            m = fmaxf(m, __shfl_xor(m, 32));
            if (quad == 0) red[w][nf*16 + l15] = m;
        }
        __syncthreads();
        {
            int c = t & 127, pd2 = t >> 7;
            float m = fmaxf(red[pd2*2][c], red[pd2*2 + 1][c]);
            ctxIn[(size_t)(g*32 + ip*2 + pd2)*1152 + 64 + ntile*128 + c] = f2b(m);
        }
    }
}

// ---------------- generic MFMA GEMM, M-tile = MF*32: out = relu(S[n]*A@BT' + Bb[n]) ----------------
template<int MF>
__global__ __launch_bounds__(256) void k_gemm_bt(
    const u16* __restrict__ A, int lda, const u16* __restrict__ BT,
    const float* __restrict__ S, const float* __restrict__ Bb,
    u16* __restrict__ out, int ldo, int K, int validN,
    const u16* __restrict__ noisep)
{
    __shared__ __align__(16) u16 Als[MF*32*72];
    __shared__ __align__(16) u16 Bls[128*72];
    const int t = threadIdx.x;
    const int m0 = blockIdx.x*(MF*32), n0 = blockIdx.y*128;
    const int w = t>>6, lane = t&63, quad = lane>>4, l15 = lane&15;
    const int rw = w>>1, cw = w&1;
    v4f acc[MF][4];
    for (int mf = 0; mf < MF; ++mf) for (int nf = 0; nf < 4; ++nf) acc[mf][nf] = (v4f){0.f,0.f,0.f,0.f};
    const int nch = K >> 6;
    for (int ch = 0; ch < nch; ++ch){
        const int k0 = ch*64;
        __syncthreads();
        if (MF == 4){
            const int srow = t>>1, sh = t&1;
            const u16* srcA = A + (size_t)(m0+srow)*lda + k0 + sh*32;
            u16* dstA = &Als[srow*72 + sh*32];
            ((v8s*)dstA)[0] = ((const v8s*)srcA)[0];
            ((v8s*)dstA)[1] = ((const v8s*)srcA)[1];
            ((v8s*)dstA)[2] = ((const v8s*)srcA)[2];
            ((v8s*)dstA)[3] = ((const v8s*)srcA)[3];
        } else {
            const int srow = t>>2, sh = t&3;
            const u16* srcA = A + (size_t)(m0+srow)*lda + k0 + sh*16;
            u16* dstA = &Als[srow*72 + sh*16];
            ((v8s*)dstA)[0] = ((const v8s*)srcA)[0];
            ((v8s*)dstA)[1] = ((const v8s*)srcA)[1];
        }
        {
            const int srow = t>>1, sh = t&1;
            const u16* srcB = BT + (size_t)(n0+srow)*K + k0 + sh*32;
            u16* dstB = &Bls[srow*72 + sh*32];
            ((v8s*)dstB)[0] = ((const v8s*)srcB)[0];
            ((v8s*)dstB)[1] = ((const v8s*)srcB)[1];
            ((v8s*)dstB)[2] = ((const v8s*)srcB)[2];
            ((v8s*)dstB)[3] = ((const v8s*)srcB)[3];
        }
        __syncthreads();
        for (int kc = 0; kc < 2; ++kc){
            v8s af[MF], bf[4];
            for (int mf = 0; mf < MF; ++mf) af[mf] = *(const v8s*)&Als[(rw*(MF*16) + mf*16 + l15)*72 + kc*32 + quad*8];
            for (int nf = 0; nf < 4; ++nf) bf[nf] = *(const v8s*)&Bls[(cw*64 + nf*16 + l15)*72 + kc*32 + quad*8];
            for (int mf = 0; mf < MF; ++mf)
                for (int nf = 0; nf < 4; ++nf)
                    acc[mf][nf] = __builtin_amdgcn_mfma_f32_16x16x32_bf16(af[mf], bf[nf], acc[mf][nf], 0, 0, 0);
        }
    }
    for (int nf = 0; nf < 4; ++nf){
        int n = n0 + cw*64 + nf*16 + l15;
        bool okn = (n < validN);
        float s = okn ? S[n] : 0.f, bb = okn ? Bb[n] : 0.f;
        bool okz = (!okn) && (noisep != nullptr) && (n < 128);
        for (int mf = 0; mf < MF; ++mf){
            int m = m0 + rw*(MF*16) + mf*16 + quad*4;
            for (int r = 0; r < 4; ++r){
                float v = fmaxf(s*acc[mf][nf][r] + bb, 0.f);
                if (okn) out[(size_t)(m+r)*ldo + n] = f2b(v);
                else if (okz) out[(size_t)(m+r)*ldo + n] = noisep[(size_t)(m+r)*8 + (n - 120)];
            }
        }
    }
}

// ---------------- decoder LSTM rollout ----------------
__global__ __launch_bounds__(256) void k_decoder(
    const u16* __restrict__ decH0, const u16* __restrict__ decF, const u16* __restrict__ decB,
    const u16* __restrict__ dembW, const u16* __restrict__ dembB,
    const u16* __restrict__ h2pW, const u16* __restrict__ h2pB,
    const u16* __restrict__ obs_rel, const u16* __restrict__ obs_speed,
    const int* __restrict__ flag, void* __restrict__ outp)
{
    __shared__ __align__(16) u16 Als[16*200];
    __shared__ float rps[16][2];
    __shared__ float sps[16];
    __shared__ float h2ps[256];
    const int t = threadIdx.x, pedbase = blockIdx.x*16;
    const int w = t>>6, lane = t&63, quad = lane>>4, l15 = lane&15;
    const int isf = *flag;
    for (int idx = t; idx < 2048; idx += 256){
        int p = idx>>7, jj = idx&127;
        Als[p*200 + 64 + jj] = decH0[(pedbase+p)*128 + jj];
    }
    h2ps[t] = b2f(h2pW[t]);
    if (t < 16) sps[t] = b2f(obs_speed[7*4096 + pedbase + t]);
    if (t < 32){ int p = t>>1, cmp = t&1; rps[p][cmp] = b2f(obs_rel[7*8192 + (pedbase+p)*2 + cmp]); }
    __syncthreads();
    {
        int p = t>>4, e0 = (t&15)*4;
        for (int e = e0; e < e0+4; ++e){
            float v = rps[p][0]*b2f(dembW[e]) + rps[p][1]*b2f(dembW[64+e]) + sps[p]*b2f(dembW[128+e]) + b2f(dembB[e]);
            Als[p*200 + e] = f2b(v);
        }
    }
    float bI[2], bF[2], bG[2], bO[2];
    for (int nfl = 0; nfl < 2; ++nfl){
        int j = w*32 + nfl*16 + l15;
        bI[nfl] = b2f(decB[j]); bF[nfl] = b2f(decB[128+j]);
        bG[nfl] = b2f(decB[256+j]); bO[nfl] = b2f(decB[384+j]);
    }
    float c8[2][4] = {{0.f,0.f,0.f,0.f},{0.f,0.f,0.f,0.f}};
    for (int s = 0; s < 12; ++s){
        __syncthreads();
        v4f acc[4][2];
        for (int q = 0; q < 4; ++q) for (int nfl = 0; nfl < 2; ++nfl) acc[q][nfl] = (v4f){0.f,0.f,0.f,0.f};
        for (int kc = 0; kc < 6; ++kc){
            v8s a = *(const v8s*)&Als[l15*200 + kc*32 + quad*8];
            for (int q = 0; q < 4; ++q){
                for (int nfl = 0; nfl < 2; ++nfl){
                    int nf = q*8 + w*2 + nfl;
                    v8s b = *(const v8s*)&decF[((nf*6 + kc)*64 + lane)*8];
                    acc[q][nfl] = __builtin_amdgcn_mfma_f32_16x16x32_bf16(a, b, acc[q][nfl], 0, 0, 0);
                }
            }
        }
        __syncthreads();
        for (int nfl = 0; nfl < 2; ++nfl){
            int j = w*32 + nfl*16 + l15;
            for (int r = 0; r < 4; ++r){
                float gi = sigm(acc[0][nfl][r] + bI[nfl]), gf = sigm(acc[1][nfl][r] + bF[nfl]);
                float gg = tanh_(acc[2][nfl][r] + bG[nfl]), go = sigm(acc[3][nfl][r] + bO[nfl]);
                c8[nfl][r] = gf*c8[nfl][r] + gi*gg;
                Als[(quad*4 + r)*200 + 64 + j] = f2b(go*tanh_(c8[nfl][r]));
            }
        }
        __syncthreads();
        {
            int p = t>>4, cmp = (t>>3)&1, part = t&7;
            float rp = 0.f;
            int j0 = part*16;
            for (int jj = j0; jj < j0+16; ++jj)
                rp += b2f(Als[p*200 + 64 + jj]) * h2ps[jj*2 + cmp];
            rp += __shfl_xor(rp, 1);
            rp += __shfl_xor(rp, 2);
            rp += __shfl_xor(rp, 4);
            if (part == 0){
                rp += b2f(h2pB[cmp]);
                int oi = s*8192 + (pedbase+p)*2 + cmp;
                if (isf) ((float*)outp)[oi] = rp;
                else     ((u16*)outp)[oi]   = f2b(rp);
                rps[p][cmp] = rp;
            }
        }
        __syncthreads();
        {
            int p = t>>4, e0 = (t&15)*4;
            for (int e = e0; e < e0+4; ++e){
                float v = rps[p][0]*b2f(dembW[e]) + rps[p][1]*b2f(dembW[64+e]) + sps[p]*b2f(dembW[128+e]) + b2f(dembB[e]);
                Als[p*200 + e] = f2b(v);
            }
        }
    }
}

extern "C" void kernel_launch(void* const* d_in, const int* in_sizes, int n_in,
                              void* d_out, int out_size, void* d_ws, size_t ws_size,
                              hipStream_t stream)
{
    (void)in_sizes; (void)n_in; (void)out_size;
    const void* obs_traj  = d_in[0];
    const void* obs_rel   = d_in[1];
    const void* obs_speed = d_in[2];
    const void* noise     = d_in[3];
    const void* enc_emb_W = d_in[4];
    const void* enc_emb_b = d_in[5];
    const void* enc_Wih   = d_in[6];
    const void* enc_Whh   = d_in[7];
    const void* enc_b     = d_in[8];
    const void* pool_sp_W = d_in[9];
    const void* pool_sp_b = d_in[10];
    const void* pool_spd_W= d_in[11];
    const void* pool_spd_b= d_in[12];
    const void* pool_l1_W = d_in[13];
    const void* pool_l1_b = d_in[14];
    const void* pool_bn1_g= d_in[15];
    const void* pool_bn1_b= d_in[16];
    const void* pool_l2_W = d_in[17];
    const void* pool_l2_b = d_in[18];
    const void* pool_bn2_g= d_in[19];
    const void* pool_bn2_b= d_in[20];
    const void* spd_emb_W = d_in[21];
    const void* spd_emb_b = d_in[22];
    const void* ctx_l1_W  = d_in[23];
    const void* ctx_l1_b  = d_in[24];
    const void* ctx_bn1_g = d_in[25];
    const void* ctx_bn1_b = d_in[26];
    const void* ctx_l2_W  = d_in[27];
    const void* ctx_l2_b  = d_in[28];
    const void* ctx_bn2_g = d_in[29];
    const void* ctx_bn2_b = d_in[30];
    const void* dec_emb_W = d_in[31];
    const void* dec_emb_b = d_in[32];
    const void* dec_Wih   = d_in[33];
    const void* dec_Whh   = d_in[34];
    const void* dec_b     = d_in[35];
    const void* h2p_W     = d_in[36];
    const void* h2p_b     = d_in[37];

    char* ws = (char*)d_ws;
    int*   flag  = (int*)  (ws + FLAG_OFF);
    float* AUX   = (float*)(ws + AUX_OFF);
    u16*   encF  = (u16*)  (ws + ENCF_OFF);
    u16*   decF  = (u16*)  (ws + DECF_OFF);
    u16*   cW2T  = (u16*)  (ws + CW2T_OFF);
    u16*   W2T   = (u16*)  (ws + W2T_OFF);
    u16*   decH  = (u16*)  (ws + DECH_OFF);
    u16*   cW1T  = (u16*)  (ws + CW1T_OFF);
    u16*   IT    = (u16*)  (ws + IT_OFF);
    u16*   IR    = (u16*)  (ws + IR_OFF);
    u16*   IS    = (u16*)  (ws + IS_OFF);
    u16*   INZ   = (u16*)  (ws + INZ_OFF);
    u16*   IW1H  = (u16*)  (ws + IW1H_OFF);
    u16*   SM    = (u16*)  (ws + SM_OFF);
    u16*   ctxIn = (u16*)  (ws + CTX_OFF);
    u16*   Avec  = (u16*)  (ws + AV_OFF);
    u16*   c1    = (u16*)  (ws + AV_OFF);   // overlays Avec (dead after k_pool)
    const bool big = (ws_size >= (size_t)BIG_NEED);

    k_prep<<<dim3(1876), dim3(256), 0, stream>>>(
        obs_traj, obs_rel, obs_speed, noise,
        enc_emb_W, enc_emb_b, enc_Wih, enc_Whh, enc_b,
        pool_sp_W, pool_sp_b, pool_spd_W, pool_spd_b,
        pool_l1_W, pool_l1_b, pool_bn1_g, pool_bn1_b,
        pool_l2_W, pool_l2_b, pool_bn2_g, pool_bn2_b,
        spd_emb_W, spd_emb_b,
        ctx_l1_W, ctx_l1_b, ctx_bn1_g, ctx_bn1_b,
        ctx_l2_W, ctx_l2_b, ctx_bn2_g, ctx_bn2_b,
        dec_emb_W, dec_emb_b, dec_Wih, dec_Whh, dec_b,
        h2p_W, h2p_b,
        flag, AUX, IT, IR, IS, INZ, IW1H, SM,
        W2T, cW1T, cW2T, encF, decF);
    k_encoder<<<dim3(256), dim3(256), 0, stream>>>(
        IR, SM + SM_EEW, SM + SM_EEB, encF, SM + SM_ENB,
        IT, IS, IW1H, SM + SM_SEW, SM + SM_SEB, AUX, ctxIn, Avec);
    k_pool<<<dim3(2048), dim3(256), 0, stream>>>(Avec, W2T, IT, AUX, ctxIn);
    if (big){
        k_gemm_bt<4><<<dim3(32, 8), dim3(256), 0, stream>>>(
            ctxIn, 1152, cW1T, AUX + 6144, AUX + 7168, c1, 1024, 1152, 1024, (const u16*)nullptr);
        k_gemm_bt<2><<<dim3(64, 1), dim3(256), 0, stream>>>(
            c1, 1024, cW2T, AUX + 8192, AUX + 8320, decH, 128, 1024, 120, INZ);
    } else {
        k_gemm_bt<4><<<dim3(16, 8), dim3(256), 0, stream>>>(
            ctxIn, 1152, cW1T, AUX + 6144, AUX + 7168, c1, 1024, 1152, 1024, (const u16*)nullptr);
        k_gemm_bt<2><<<dim3(32, 1), dim3(256), 0, stream>>>(
            c1, 1024, cW2T, AUX + 8192, AUX + 8320, decH, 128, 1024, 120, INZ);
        k_gemm_bt<4><<<dim3(16, 8), dim3(256), 0, stream>>>(
            ctxIn + (size_t)2048*1152, 1152, cW1T, AUX + 6144, AUX + 7168, c1, 1024, 1152, 1024, (const u16*)nullptr);
        k_gemm_bt<2><<<dim3(32, 1), dim3(256), 0, stream>>>(
            c1, 1024, cW2T, AUX + 8192, AUX + 8320, decH + (size_t)2048*128, 128, 1024, 120, INZ + (size_t)2048*8);
    }
    k_decoder<<<dim3(256), dim3(256), 0, stream>>>(
        decH, decF, SM + SM_DNB, SM + SM_DEW, SM + SM_DEB,
        SM + SM_H2W, SM + SM_H2B, IR, IS, flag, d_out);
}

// Round 10
// 438.198 us; speedup vs baseline: 1.1538x; 1.1241x over previous
//
#include <hip/hip_runtime.h>

typedef __attribute__((ext_vector_type(8))) short v8s;
typedef __attribute__((ext_vector_type(4))) float v4f;
typedef unsigned short u16;

#define DINL static __device__ __forceinline__

DINL float b2f(u16 u){ union { unsigned uu; float ff; } x; x.uu = ((unsigned)u)<<16; return x.ff; }
DINL u16 f2b(float f){ union { float ff; unsigned uu; } x; x.ff = f; unsigned r = x.uu + 0x7FFFu + ((x.uu>>16)&1u); return (u16)(r>>16); }
DINL u16 f2b_hu(float f){ union { float ff; unsigned uu; } x; x.ff = f; return (u16)((x.uu + 0x8000u)>>16); }
DINL float sigm(float x){ return 1.0f/(1.0f+__expf(-x)); }
DINL float tanh_(float x){ return 2.0f/(1.0f+__expf(-2.0f*x)) - 1.0f; }
DINL float ld(const void* p, int i, int isf){
    return isf ? ((const float*)p)[i] : b2f(((const u16*)p)[i]);
}
DINL void g2lds16(const u16* g, u16* l){
    __builtin_amdgcn_global_load_lds(
        (const __attribute__((address_space(1))) unsigned int*)g,
        (__attribute__((address_space(3))) unsigned int*)l, 16, 0, 0);
}
DINL int detect_isf(const void* obs_speed){
    const u16* p = (const u16*)obs_speed;
    int f = 0;
    for (int i = 0; i < 16; ++i){
        u16 v = p[2*i];
        if ((v & 0x8000u) || v > 0x3F80u) f = 1;
    }
    return f;
}

// ---- workspace byte offsets ----
#define FLAG_OFF 0x000000
#define AUX_OFF  0x000100
#define ENCF_OFF 0x010000
#define DECF_OFF 0x020000
#define CW2T_OFF 0x050000
#define W2T_OFF  0x090000   // dead after k_pool; decH overlays
#define DECH_OFF 0x090000
#define CW1T_OFF 0x190000
#define IT_OFF   0x3D0000
#define IR_OFF   0x3F0000
#define IS_OFF   0x410000
#define INZ_OFF  0x420000
#define IW1H_OFF 0x430000
#define SM_OFF   0x440000
#define CTX_OFF  0x450000   // ctx_in 4096x1152 bf16
#define AV_OFF   0xD50000   // Avec bf16 (dead after k_pool); c1 overlays
#define BIG_NEED 0x1550000  // AV_OFF + 8MB single-pass c1

#define SM_EEW 0
#define SM_EEB 128
#define SM_ENB 192
#define SM_DEW 448
#define SM_DEB 640
#define SM_DNB 704
#define SM_H2W 1216
#define SM_H2B 1472
#define SM_SEW 1536
#define SM_SEB 2048

// ---------------- unified prep kernel ----------------
DINL void trans_tile(const void* in, u16* out, int K, int N, int isf,
                     int bx, int by, int t, float tile[64][65])
{
    const int nbase = bx*64, kbase = by*64;
    const int c = t & 63, r0 = (t >> 6)*16;
    for (int rep = 0; rep < 16; ++rep){
        int r = r0 + rep;
        int n = nbase + c;
        float v = 0.f;
        if (n < N) v = ld(in, (kbase + r)*N + n, isf);
        tile[r][c] = v;
    }
    __syncthreads();
    for (int rep = 0; rep < 16; ++rep){
        int r = r0 + rep;
        out[(size_t)(nbase + r)*K + kbase + c] = f2b(tile[c][r]);
    }
}

__global__ __launch_bounds__(256) void k_prep(
    const void* obs_traj, const void* obs_rel, const void* obs_speed, const void* noise,
    const void* eeW, const void* eeB, const void* enc_Wih, const void* enc_Whh, const void* encB,
    const void* spW, const void* spB, const void* spdW, const void* spdB,
    const void* pool_l1_W, const void* l1B, const void* bn1g, const void* bn1b,
    const void* pool_l2_W, const void* l2b, const void* bn2g, const void* bn2b,
    const void* seW, const void* seB,
    const void* ctx_l1_W, const void* c1b, const void* cbn1g, const void* cbn1b,
    const void* ctx_l2_W, const void* c2b, const void* cbn2g, const void* cbn2b,
    const void* deW, const void* deB, const void* dec_Wih, const void* dec_Whh, const void* decB,
    const void* h2W, const void* h2B,
    int* flag, float* AUX,
    u16* IT, u16* IR, u16* IS, u16* INZ, u16* IW1H, u16* SM,
    u16* W2T, u16* cW1T, u16* cW2T, u16* encF, u16* decF)
{
    __shared__ float tile[64][65];
    __shared__ int sisf;
    const int t = threadIdx.x;
    if (t == 0){
        int f = detect_isf(obs_speed);
        sisf = f;
        if (blockIdx.x == 0) *flag = f;
    }
    __syncthreads();
    const int isf = sisf;
    int bid = blockIdx.x;
    if (bid < 905){
        int idx = bid*256 + t;
        if (idx < 65536){ IT[idx] = f2b(ld(obs_traj, idx, isf)); return; }
        idx -= 65536;
        if (idx < 65536){ IR[idx] = f2b(ld(obs_rel, idx, isf)); return; }
        idx -= 65536;
        if (idx < 32768){ IS[idx] = f2b(ld(obs_speed, idx, isf)); return; }
        idx -= 32768;
        if (idx < 32768){ INZ[idx] = f2b(ld(noise, idx, isf)); return; }
        idx -= 32768;
        if (idx < 32768){ IW1H[idx] = f2b(ld(pool_l1_W, idx + 32768, isf)); return; }
        idx -= 32768;
        if (idx < 128){ SM[SM_EEW + idx] = f2b(ld(eeW, idx, isf)); return; }
        idx -= 128;
        if (idx < 64){ SM[SM_EEB + idx] = f2b(ld(eeB, idx, isf)); return; }
        idx -= 64;
        if (idx < 256){ SM[SM_ENB + idx] = f2b(ld(encB, idx, isf)); return; }
        idx -= 256;
        if (idx < 192){ SM[SM_DEW + idx] = f2b(ld(deW, idx, isf)); return; }
        idx -= 192;
        if (idx < 64){ SM[SM_DEB + idx] = f2b(ld(deB, idx, isf)); return; }
        idx -= 64;
        if (idx < 512){ SM[SM_DNB + idx] = f2b(ld(decB, idx, isf)); return; }
        idx -= 512;
        if (idx < 256){ SM[SM_H2W + idx] = f2b(ld(h2W, idx, isf)); return; }
        idx -= 256;
        if (idx < 2){ SM[SM_H2B + idx] = f2b(ld(h2B, idx, isf)); return; }
        idx -= 2;
        if (idx < 512){ SM[SM_SEW + idx] = f2b(ld(seW, idx, isf)); return; }
        idx -= 512;
        if (idx < 64){ SM[SM_SEB + idx] = f2b(ld(seB, idx, isf)); return; }
        return;
    }
    bid -= 905;
    if (bid < 512){
        int idx = bid*256 + t;
        if (idx < 32768){
            int jj = idx&7, lane = (idx>>3)&63, kcnf = idx>>9;
            int kc = kcnf&3, nf = kcnf>>2;
            int k = kc*32 + (lane>>4)*8 + jj, n = nf*16 + (lane&15);
            encF[idx] = (k < 64) ? f2b(ld(enc_Wih, k*256+n, isf)) : f2b(ld(enc_Whh, (k-64)*256+n, isf));
        } else {
            idx -= 32768;
            int jj = idx&7, lane = (idx>>3)&63, kcnf = idx>>9;
            int kc = kcnf % 6, nf = kcnf / 6;
            int k = kc*32 + (lane>>4)*8 + jj, n = nf*16 + (lane&15);
            decF[idx] = (k < 64) ? f2b(ld(dec_Wih, k*512+n, isf)) : f2b(ld(dec_Whh, (k-64)*512+n, isf));
        }
        return;
    }
    bid -= 512;
    if (bid < 128){ trans_tile(pool_l2_W, W2T, 512, 1024, isf, bid & 15, bid >> 4, t, tile); return; }
    bid -= 128;
    if (bid < 288){ trans_tile(ctx_l1_W, cW1T, 1152, 1024, isf, bid & 15, bid >> 4, t, tile); return; }
    bid -= 288;
    if (bid < 32){ trans_tile(ctx_l2_W, cW2T, 1024, 120, isf, bid & 1, bid >> 1, t, tile); return; }
    bid -= 32;
    {
        int idx = bid*256 + t;
        if (idx < 512){
            int c = idx;
            float m0 = 0.f, m1 = 0.f, qv = 0.f, cv = 0.f;
            for (int e = 0; e < 64; ++e){
                float w1a = ld(pool_l1_W, e*512 + c, isf);
                m0 += ld(spW, e, isf)*w1a;
                m1 += ld(spW, 64+e, isf)*w1a;
                cv += ld(spB, e, isf)*w1a;
                float w1c = ld(pool_l1_W, (128+e)*512 + c, isf);
                qv += ld(spdW, e, isf)*w1c;
                cv += ld(spdB, e, isf)*w1c;
            }
            cv += ld(l1B, c, isf);
            float g1 = ld(bn1g, c, isf), bb1 = ld(bn1b, c, isf);
            AUX[c] = m0; AUX[512+c] = m1; AUX[1024+c] = qv; AUX[1536+c] = cv;
            AUX[2048+c] = g1; AUX[2560+c] = bb1;
            AUX[3072+c] = g1*m0; AUX[3584+c] = g1*m1;
            return;
        }
        idx -= 512;
        if (idx < 1024){
            float g = ld(bn2g, idx, isf);
            AUX[4096+idx] = g; AUX[5120+idx] = ld(l2b, idx, isf)*g + ld(bn2b, idx, isf);
            return;
        }
        idx -= 1024;
        if (idx < 1024){
            float g = ld(cbn1g, idx, isf);
            AUX[6144+idx] = g; AUX[7168+idx] = ld(c1b, idx, isf)*g + ld(cbn1b, idx, isf);
            return;
        }
        idx -= 1024;
        if (idx < 128){
            int c = idx;
            float g  = (c < 120) ? ld(cbn2g, c, isf) : 1.f;
            float bb = (c < 120) ? (ld(c2b, c, isf)*g + ld(cbn2b, c, isf)) : 0.f;
            AUX[8192+c] = g; AUX[8320+c] = bb;
        }
    }
}

// ---------------- encoder LSTM (16 peds/block) + fused Avec + speed-context ----------------
__global__ __launch_bounds__(256) void k_encoder(
    const u16* __restrict__ rel, const u16* __restrict__ embW, const u16* __restrict__ embB,
    const u16* __restrict__ encF, const u16* __restrict__ encB,
    const u16* __restrict__ IT, const u16* __restrict__ IS, const u16* __restrict__ IW1H,
    const u16* __restrict__ sW, const u16* __restrict__ sB,
    const float* __restrict__ AUX,
    u16* __restrict__ ctxIn, u16* __restrict__ Avec)
{
    __shared__ __align__(16) u16 Als[16*136];
    __shared__ float pxs[16], pys[16], sps[16];
    const int t = threadIdx.x, pedbase = blockIdx.x*16;
    const int w = t>>6, lane = t&63, quad = lane>>4, l15 = lane&15;
    for (int idx = t; idx < 16*64; idx += 256){ int p = idx>>6, jj = idx&63; Als[p*136 + 64 + jj] = 0; }
    if (t < 16){
        pxs[t] = b2f(IT[7*8192 + (pedbase+t)*2 + 0]);
        pys[t] = b2f(IT[7*8192 + (pedbase+t)*2 + 1]);
        sps[t] = b2f(IS[7*4096 + pedbase + t]);
    }
    {
        int p = t>>4, e0 = (t&15)*4;
        float rx = b2f(rel[(pedbase+p)*2 + 0]);
        float ry = b2f(rel[(pedbase+p)*2 + 1]);
        for (int e = e0; e < e0+4; ++e)
            Als[p*136 + e] = f2b(rx*b2f(embW[e]) + ry*b2f(embW[64+e]) + b2f(embB[e]));
    }
    const int j = w*16 + l15;
    const float bi = b2f(encB[j]), bff = b2f(encB[64+j]), bg = b2f(encB[128+j]), bo = b2f(encB[192+j]);
    float c4[4] = {0.f,0.f,0.f,0.f};
    for (int step = 0; step < 8; ++step){
        __syncthreads();
        v4f acc[4];
        for (int q = 0; q < 4; ++q) acc[q] = (v4f){0.f,0.f,0.f,0.f};
        for (int kc = 0; kc < 4; ++kc){
            v8s a = *(const v8s*)&Als[l15*136 + kc*32 + quad*8];
            for (int q = 0; q < 4; ++q){
                int nf = q*4 + w;
                v8s b = *(const v8s*)&encF[((nf*4 + kc)*64 + lane)*8];
                acc[q] = __builtin_amdgcn_mfma_f32_16x16x32_bf16(a, b, acc[q], 0, 0, 0);
            }
        }
        __syncthreads();
        for (int r = 0; r < 4; ++r){
            float gi = sigm(acc[0][r] + bi), gf = sigm(acc[1][r] + bff);
            float gg = tanh_(acc[2][r] + bg), go = sigm(acc[3][r] + bo);
            c4[r] = gf*c4[r] + gi*gg;
            Als[(quad*4 + r)*136 + 64 + j] = f2b(go*tanh_(c4[r]));
        }
        if (step < 7){
            int p = t>>4, e0 = (t&15)*4;
            float rx = b2f(rel[(step+1)*8192 + (pedbase+p)*2 + 0]);
            float ry = b2f(rel[(step+1)*8192 + (pedbase+p)*2 + 1]);
            for (int e = e0; e < e0+4; ++e)
                Als[p*136 + e] = f2b(rx*b2f(embW[e]) + ry*b2f(embW[64+e]) + b2f(embB[e]));
        }
    }
    __syncthreads();
    for (int idx = t; idx < 1024; idx += 256){
        int p = idx>>6, e = idx&63;
        ctxIn[(size_t)(pedbase+p)*1152 + e] = Als[p*136 + 64 + e];
    }
    {
        const int c0 = (t&127)*4, pg = (t>>7)*8;
        float4 acc[8];
        for (int p = 0; p < 8; ++p) acc[p] = make_float4(0.f,0.f,0.f,0.f);
        for (int e = 0; e < 64; ++e){
            ushort4 wv = *(const ushort4*)(IW1H + e*512 + c0);
            float w0 = b2f(wv.x), w1 = b2f(wv.y), w2 = b2f(wv.z), w3 = b2f(wv.w);
            for (int p = 0; p < 8; ++p){
                float h = b2f(Als[(pg+p)*136 + 64 + e]);
                acc[p].x += h*w0; acc[p].y += h*w1; acc[p].z += h*w2; acc[p].w += h*w3;
            }
        }
        float4 m0 = *(const float4*)(AUX + c0),        m1 = *(const float4*)(AUX + 512 + c0);
        float4 qv = *(const float4*)(AUX + 1024 + c0), cv = *(const float4*)(AUX + 1536 + c0);
        float4 g1 = *(const float4*)(AUX + 2048 + c0), bb = *(const float4*)(AUX + 2560 + c0);
        for (int p = 0; p < 8; ++p){
            float px = pxs[pg+p], py = pys[pg+p], sp = sps[pg+p];
            ushort4 o;
            o.x = f2b(g1.x*(px*m0.x + py*m1.x + sp*qv.x + cv.x + acc[p].x) + bb.x);
            o.y = f2b(g1.y*(px*m0.y + py*m1.y + sp*qv.y + cv.y + acc[p].y) + bb.y);
            o.z = f2b(g1.z*(px*m0.z + py*m1.z + sp*qv.z + cv.z + acc[p].z) + bb.z);
            o.w = f2b(g1.w*(px*m0.w + py*m1.w + sp*qv.w + cv.w + acc[p].w) + bb.w);
            *(ushort4*)&Avec[(size_t)(pedbase+pg+p)*512 + c0] = o;
        }
    }
    {
        int s = t & 63;
        for (int rep = 0; rep < 4; ++rep){
            int p = (t>>6)*4 + rep;
            int nid = pedbase + p;
            float a = b2f(sB[s]);
            for (int tt = 0; tt < 8; ++tt) a += b2f(IS[tt*4096 + nid]) * b2f(sW[tt*64 + s]);
            ctxIn[(size_t)nid*1152 + 1088 + s] = f2b(sigm(a));
        }
    }
}

// ---------------- pool GEMM v4 (round-6 best): M=64 (2 peds x 32 j), N=256, 3 blocks/CU ----------------
// A-tile built in LDS per (chunk, n-block); the build VALU doubles as latency hiding for the
// async B stage. Empirically best: v5/v6/v7 variants that removed the build all stall-bound.
__global__ __launch_bounds__(256, 3) void k_pool(
    const u16* __restrict__ Avec, const u16* __restrict__ W2T,
    const u16* __restrict__ IT, const float* __restrict__ AUX,
    u16* __restrict__ ctxIn)
{
    __shared__ __align__(16) u16 Als[64*72];      // A-tile, pad-72 (16B rows)
    __shared__ __align__(16) u16 Bls[256*64];     // B-tile, XOR-swizzled granules
    __shared__ float auxM[1024];                  // M0G | M1G
    __shared__ float pxs[2], pys[2];
    const int t = threadIdx.x;
    const int g = blockIdx.x >> 4, ip = blockIdx.x & 15;
    const int n0 = blockIdx.y * 256;
    const int w = t>>6, lane = t&63, quad = lane>>4, l15 = lane&15;
    const int aj = t>>3, ao = t&7;
    for (int i = t; i < 1024; i += 256) auxM[i] = AUX[3072 + i];
    if (t < 2){
        pxs[t] = b2f(IT[7*8192 + (g*32 + ip*2 + t)*2 + 0]);
        pys[t] = b2f(IT[7*8192 + (g*32 + ip*2 + t)*2 + 1]);
    }
    const u16* bsrc = W2T + (size_t)(n0 + w*8 + (lane>>3))*512 + (size_t)(((lane&7) ^ (lane>>3)))*8;
    u16* bdst = &Bls[w*512];
    const u16* arow = Avec + (size_t)(g*32+aj)*512 + ao*8;
    v4f acc[4][4];
    for (int mf = 0; mf < 4; ++mf) for (int nf = 0; nf < 4; ++nf) acc[mf][nf] = (v4f){0.f,0.f,0.f,0.f};
    union { v8s v; u16 u[8]; } av;
    av.v = *(const v8s*)arow;                      // prefetch chunk 0
    for (int ch = 0; ch < 8; ++ch){
        const int k0 = ch*64;
        __syncthreads();
        for (int it = 0; it < 8; ++it)
            g2lds16(bsrc + k0 + it*16384, bdst + it*2048);
        {   // A build from prefetched registers
            float a0[8], m0a[8], m1a[8];
            for (int i = 0; i < 8; ++i) a0[i] = b2f(av.u[i]);
            *(float4*)(m0a)   = *(const float4*)&auxM[k0 + ao*8];
            *(float4*)(m0a+4) = *(const float4*)&auxM[k0 + ao*8 + 4];
            *(float4*)(m1a)   = *(const float4*)&auxM[512 + k0 + ao*8];
            *(float4*)(m1a+4) = *(const float4*)&auxM[512 + k0 + ao*8 + 4];
            for (int il = 0; il < 2; ++il){
                float npx = -pxs[il], npy = -pys[il];
                union { v8s v; u16 u[8]; } pk;
                for (int i = 0; i < 8; ++i){
                    float v = __builtin_fmaf(npy, m1a[i], __builtin_fmaf(npx, m0a[i], a0[i]));
                    pk.u[i] = f2b_hu(fmaxf(v, 0.f));
                }
                *(v8s*)&Als[(il*32+aj)*72 + ao*8] = pk.v;
            }
        }
        if (ch < 7) av.v = *(const v8s*)(arow + (ch+1)*64);   // prefetch next
        __syncthreads();
        for (int kc = 0; kc < 2; ++kc){
            v8s af[4];
            for (int mf = 0; mf < 4; ++mf)
                af[mf] = *(const v8s*)&Als[(mf*16 + l15)*72 + kc*32 + quad*8];
            const int sl = ((kc*4 + quad) ^ (l15&7))*8;
            #pragma unroll
            for (int nf = 0; nf < 4; ++nf){
                v8s bf = *(const v8s*)&Bls[(w*64 + nf*16 + l15)*64 + sl];
                acc[0][nf] = __builtin_amdgcn_mfma_f32_16x16x32_bf16(af[0], bf, acc[0][nf], 0, 0, 0);
                acc[1][nf] = __builtin_amdgcn_mfma_f32_16x16x32_bf16(af[1], bf, acc[1][nf], 0, 0, 0);
                acc[2][nf] = __builtin_amdgcn_mfma_f32_16x16x32_bf16(af[2], bf, acc[2][nf], 0, 0, 0);
                acc[3][nf] = __builtin_amdgcn_mfma_f32_16x16x32_bf16(af[3], bf, acc[3][nf], 0, 0, 0);
            }
        }
    }
    const float* S2 = AUX + 4096; const float* B2 = AUX + 5120;
    for (int nf = 0; nf < 4; ++nf){
        int n = n0 + w*64 + nf*16 + l15;
        float s = S2[n], bb = B2[n];
        float mm0 = 0.f, mm1 = 0.f;
        for (int mf = 0; mf < 2; ++mf) for (int r = 0; r < 4; ++r) mm0 = fmaxf(mm0, fmaxf(s*acc[mf][nf][r] + bb, 0.f));
        for (int mf = 2; mf < 4; ++mf) for (int r = 0; r < 4; ++r) mm1 = fmaxf(mm1, fmaxf(s*acc[mf][nf][r] + bb, 0.f));
        mm0 = fmaxf(mm0, __shfl_xor(mm0, 16)); mm0 = fmaxf(mm0, __shfl_xor(mm0, 32));
        mm1 = fmaxf(mm1, __shfl_xor(mm1, 16)); mm1 = fmaxf(mm1, __shfl_xor(mm1, 32));
        if (quad == 0) ctxIn[(size_t)(g*32 + ip*2 + 0)*1152 + 64 + n] = f2b(mm0);
        if (quad == 1) ctxIn[(size_t)(g*32 + ip*2 + 1)*1152 + 64 + n] = f2b(mm1);
    }
}

// ---------------- generic MFMA GEMM, M-tile = MF*32: out = relu(S[n]*A@BT' + Bb[n]) ----------------
template<int MF>
__global__ __launch_bounds__(256) void k_gemm_bt(
    const u16* __restrict__ A, int lda, const u16* __restrict__ BT,
    const float* __restrict__ S, const float* __restrict__ Bb,
    u16* __restrict__ out, int ldo, int K, int validN,
    const u16* __restrict__ noisep)
{
    __shared__ __align__(16) u16 Als[MF*32*72];
    __shared__ __align__(16) u16 Bls[128*72];
    const int t = threadIdx.x;
    const int m0 = blockIdx.x*(MF*32), n0 = blockIdx.y*128;
    const int w = t>>6, lane = t&63, quad = lane>>4, l15 = lane&15;
    const int rw = w>>1, cw = w&1;
    v4f acc[MF][4];
    for (int mf = 0; mf < MF; ++mf) for (int nf = 0; nf < 4; ++nf) acc[mf][nf] = (v4f){0.f,0.f,0.f,0.f};
    const int nch = K >> 6;
    for (int ch = 0; ch < nch; ++ch){
        const int k0 = ch*64;
        __syncthreads();
        if (MF == 4){
            const int srow = t>>1, sh = t&1;
            const u16* srcA = A + (size_t)(m0+srow)*lda + k0 + sh*32;
            u16* dstA = &Als[srow*72 + sh*32];
            ((v8s*)dstA)[0] = ((const v8s*)srcA)[0];
            ((v8s*)dstA)[1] = ((const v8s*)srcA)[1];
            ((v8s*)dstA)[2] = ((const v8s*)srcA)[2];
            ((v8s*)dstA)[3] = ((const v8s*)srcA)[3];
        } else {
            const int srow = t>>2, sh = t&3;
            const u16* srcA = A + (size_t)(m0+srow)*lda + k0 + sh*16;
            u16* dstA = &Als[srow*72 + sh*16];
            ((v8s*)dstA)[0] = ((const v8s*)srcA)[0];
            ((v8s*)dstA)[1] = ((const v8s*)srcA)[1];
        }
        {
            const int srow = t>>1, sh = t&1;
            const u16* srcB = BT + (size_t)(n0+srow)*K + k0 + sh*32;
            u16* dstB = &Bls[srow*72 + sh*32];
            ((v8s*)dstB)[0] = ((const v8s*)srcB)[0];
            ((v8s*)dstB)[1] = ((const v8s*)srcB)[1];
            ((v8s*)dstB)[2] = ((const v8s*)srcB)[2];
            ((v8s*)dstB)[3] = ((const v8s*)srcB)[3];
        }
        __syncthreads();
        for (int kc = 0; kc < 2; ++kc){
            v8s af[MF], bf[4];
            for (int mf = 0; mf < MF; ++mf) af[mf] = *(const v8s*)&Als[(rw*(MF*16) + mf*16 + l15)*72 + kc*32 + quad*8];
            for (int nf = 0; nf < 4; ++nf) bf[nf] = *(const v8s*)&Bls[(cw*64 + nf*16 + l15)*72 + kc*32 + quad*8];
            for (int mf = 0; mf < MF; ++mf)
                for (int nf = 0; nf < 4; ++nf)
                    acc[mf][nf] = __builtin_amdgcn_mfma_f32_16x16x32_bf16(af[mf], bf[nf], acc[mf][nf], 0, 0, 0);
        }
    }
    for (int nf = 0; nf < 4; ++nf){
        int n = n0 + cw*64 + nf*16 + l15;
        bool okn = (n < validN);
        float s = okn ? S[n] : 0.f, bb = okn ? Bb[n] : 0.f;
        bool okz = (!okn) && (noisep != nullptr) && (n < 128);
        for (int mf = 0; mf < MF; ++mf){
            int m = m0 + rw*(MF*16) + mf*16 + quad*4;
            for (int r = 0; r < 4; ++r){
                float v = fmaxf(s*acc[mf][nf][r] + bb, 0.f);
                if (okn) out[(size_t)(m+r)*ldo + n] = f2b(v);
                else if (okz) out[(size_t)(m+r)*ldo + n] = noisep[(size_t)(m+r)*8 + (n - 120)];
            }
        }
    }
}

// ---------------- decoder LSTM rollout ----------------
__global__ __launch_bounds__(256) void k_decoder(
    const u16* __restrict__ decH0, const u16* __restrict__ decF, const u16* __restrict__ decB,
    const u16* __restrict__ dembW, const u16* __restrict__ dembB,
    const u16* __restrict__ h2pW, const u16* __restrict__ h2pB,
    const u16* __restrict__ obs_rel, const u16* __restrict__ obs_speed,
    const int* __restrict__ flag, void* __restrict__ outp)
{
    __shared__ __align__(16) u16 Als[16*200];
    __shared__ float rps[16][2];
    __shared__ float sps[16];
    __shared__ float h2ps[256];
    const int t = threadIdx.x, pedbase = blockIdx.x*16;
    const int w = t>>6, lane = t&63, quad = lane>>4, l15 = lane&15;
    const int isf = *flag;
    for (int idx = t; idx < 2048; idx += 256){
        int p = idx>>7, jj = idx&127;
        Als[p*200 + 64 + jj] = decH0[(pedbase+p)*128 + jj];
    }
    h2ps[t] = b2f(h2pW[t]);
    if (t < 16) sps[t] = b2f(obs_speed[7*4096 + pedbase + t]);
    if (t < 32){ int p = t>>1, cmp = t&1; rps[p][cmp] = b2f(obs_rel[7*8192 + (pedbase+p)*2 + cmp]); }
    __syncthreads();
    {
        int p = t>>4, e0 = (t&15)*4;
        for (int e = e0; e < e0+4; ++e){
            float v = rps[p][0]*b2f(dembW[e]) + rps[p][1]*b2f(dembW[64+e]) + sps[p]*b2f(dembW[128+e]) + b2f(dembB[e]);
            Als[p*200 + e] = f2b(v);
        }
    }
    float bI[2], bF[2], bG[2], bO[2];
    for (int nfl = 0; nfl < 2; ++nfl){
        int j = w*32 + nfl*16 + l15;
        bI[nfl] = b2f(decB[j]); bF[nfl] = b2f(decB[128+j]);
        bG[nfl] = b2f(decB[256+j]); bO[nfl] = b2f(decB[384+j]);
    }
    float c8[2][4] = {{0.f,0.f,0.f,0.f},{0.f,0.f,0.f,0.f}};
    for (int s = 0; s < 12; ++s){
        __syncthreads();
        v4f acc[4][2];
        for (int q = 0; q < 4; ++q) for (int nfl = 0; nfl < 2; ++nfl) acc[q][nfl] = (v4f){0.f,0.f,0.f,0.f};
        for (int kc = 0; kc < 6; ++kc){
            v8s a = *(const v8s*)&Als[l15*200 + kc*32 + quad*8];
            for (int q = 0; q < 4; ++q){
                for (int nfl = 0; nfl < 2; ++nfl){
                    int nf = q*8 + w*2 + nfl;
                    v8s b = *(const v8s*)&decF[((nf*6 + kc)*64 + lane)*8];
                    acc[q][nfl] = __builtin_amdgcn_mfma_f32_16x16x32_bf16(a, b, acc[q][nfl], 0, 0, 0);
                }
            }
        }
        __syncthreads();
        for (int nfl = 0; nfl < 2; ++nfl){
            int j = w*32 + nfl*16 + l15;
            for (int r = 0; r < 4; ++r){
                float gi = sigm(acc[0][nfl][r] + bI[nfl]), gf = sigm(acc[1][nfl][r] + bF[nfl]);
                float gg = tanh_(acc[2][nfl][r] + bG[nfl]), go = sigm(acc[3][nfl][r] + bO[nfl]);
                c8[nfl][r] = gf*c8[nfl][r] + gi*gg;
                Als[(quad*4 + r)*200 + 64 + j] = f2b(go*tanh_(c8[nfl][r]));
            }
        }
        __syncthreads();
        {
            int p = t>>4, cmp = (t>>3)&1, part = t&7;
            float rp = 0.f;
            int j0 = part*16;
            for (int jj = j0; jj < j0+16; ++jj)
                rp += b2f(Als[p*200 + 64 + jj]) * h2ps[jj*2 + cmp];
            rp += __shfl_xor(rp, 1);
            rp += __shfl_xor(rp, 2);
            rp += __shfl_xor(rp, 4);
            if (part == 0){
                rp += b2f(h2pB[cmp]);
                int oi = s*8192 + (pedbase+p)*2 + cmp;
                if (isf) ((float*)outp)[oi] = rp;
                else     ((u16*)outp)[oi]   = f2b(rp);
                rps[p][cmp] = rp;
            }
        }
        __syncthreads();
        {
            int p = t>>4, e0 = (t&15)*4;
            for (int e = e0; e < e0+4; ++e){
                float v = rps[p][0]*b2f(dembW[e]) + rps[p][1]*b2f(dembW[64+e]) + sps[p]*b2f(dembW[128+e]) + b2f(dembB[e]);
                Als[p*200 + e] = f2b(v);
            }
        }
    }
}

extern "C" void kernel_launch(void* const* d_in, const int* in_sizes, int n_in,
                              void* d_out, int out_size, void* d_ws, size_t ws_size,
                              hipStream_t stream)
{
    (void)in_sizes; (void)n_in; (void)out_size;
    const void* obs_traj  = d_in[0];
    const void* obs_rel   = d_in[1];
    const void* obs_speed = d_in[2];
    const void* noise     = d_in[3];
    const void* enc_emb_W = d_in[4];
    const void* enc_emb_b = d_in[5];
    const void* enc_Wih   = d_in[6];
    const void* enc_Whh   = d_in[7];
    const void* enc_b     = d_in[8];
    const void* pool_sp_W = d_in[9];
    const void* pool_sp_b = d_in[10];
    const void* pool_spd_W= d_in[11];
    const void* pool_spd_b= d_in[12];
    const void* pool_l1_W = d_in[13];
    const void* pool_l1_b = d_in[14];
    const void* pool_bn1_g= d_in[15];
    const void* pool_bn1_b= d_in[16];
    const void* pool_l2_W = d_in[17];
    const void* pool_l2_b = d_in[18];
    const void* pool_bn2_g= d_in[19];
    const void* pool_bn2_b= d_in[20];
    const void* spd_emb_W = d_in[21];
    const void* spd_emb_b = d_in[22];
    const void* ctx_l1_W  = d_in[23];
    const void* ctx_l1_b  = d_in[24];
    const void* ctx_bn1_g = d_in[25];
    const void* ctx_bn1_b = d_in[26];
    const void* ctx_l2_W  = d_in[27];
    const void* ctx_l2_b  = d_in[28];
    const void* ctx_bn2_g = d_in[29];
    const void* ctx_bn2_b = d_in[30];
    const void* dec_emb_W = d_in[31];
    const void* dec_emb_b = d_in[32];
    const void* dec_Wih   = d_in[33];
    const void* dec_Whh   = d_in[34];
    const void* dec_b     = d_in[35];
    const void* h2p_W     = d_in[36];
    const void* h2p_b     = d_in[37];

    char* ws = (char*)d_ws;
    int*   flag  = (int*)  (ws + FLAG_OFF);
    float* AUX   = (float*)(ws + AUX_OFF);
    u16*   encF  = (u16*)  (ws + ENCF_OFF);
    u16*   decF  = (u16*)  (ws + DECF_OFF);
    u16*   cW2T  = (u16*)  (ws + CW2T_OFF);
    u16*   W2T   = (u16*)  (ws + W2T_OFF);
    u16*   decH  = (u16*)  (ws + DECH_OFF);
    u16*   cW1T  = (u16*)  (ws + CW1T_OFF);
    u16*   IT    = (u16*)  (ws + IT_OFF);
    u16*   IR    = (u16*)  (ws + IR_OFF);
    u16*   IS    = (u16*)  (ws + IS_OFF);
    u16*   INZ   = (u16*)  (ws + INZ_OFF);
    u16*   IW1H  = (u16*)  (ws + IW1H_OFF);
    u16*   SM    = (u16*)  (ws + SM_OFF);
    u16*   ctxIn = (u16*)  (ws + CTX_OFF);
    u16*   Avec  = (u16*)  (ws + AV_OFF);
    u16*   c1    = (u16*)  (ws + AV_OFF);   // overlays Avec (dead after k_pool)
    const bool big = (ws_size >= (size_t)BIG_NEED);

    k_prep<<<dim3(1876), dim3(256), 0, stream>>>(
        obs_traj, obs_rel, obs_speed, noise,
        enc_emb_W, enc_emb_b, enc_Wih, enc_Whh, enc_b,
        pool_sp_W, pool_sp_b, pool_spd_W, pool_spd_b,
        pool_l1_W, pool_l1_b, pool_bn1_g, pool_bn1_b,
        pool_l2_W, pool_l2_b, pool_bn2_g, pool_bn2_b,
        spd_emb_W, spd_emb_b,
        ctx_l1_W, ctx_l1_b, ctx_bn1_g, ctx_bn1_b,
        ctx_l2_W, ctx_l2_b, ctx_bn2_g, ctx_bn2_b,
        dec_emb_W, dec_emb_b, dec_Wih, dec_Whh, dec_b,
        h2p_W, h2p_b,
        flag, AUX, IT, IR, IS, INZ, IW1H, SM,
        W2T, cW1T, cW2T, encF, decF);
    k_encoder<<<dim3(256), dim3(256), 0, stream>>>(
        IR, SM + SM_EEW, SM + SM_EEB, encF, SM + SM_ENB,
        IT, IS, IW1H, SM + SM_SEW, SM + SM_SEB, AUX, ctxIn, Avec);
    k_pool<<<dim3(2048, 4), dim3(256), 0, stream>>>(Avec, W2T, IT, AUX, ctxIn);
    if (big){
        k_gemm_bt<4><<<dim3(32, 8), dim3(256), 0, stream>>>(
            ctxIn, 1152, cW1T, AUX + 6144, AUX + 7168, c1, 1024, 1152, 1024, (const u16*)nullptr);
        k_gemm_bt<2><<<dim3(64, 1), dim3(256), 0, stream>>>(
            c1, 1024, cW2T, AUX + 8192, AUX + 8320, decH, 128, 1024, 120, INZ);
    } else {
        k_gemm_bt<4><<<dim3(16, 8), dim3(256), 0, stream>>>(
            ctxIn, 1152, cW1T, AUX + 6144, AUX + 7168, c1, 1024, 1152, 1024, (const u16*)nullptr);
        k_gemm_bt<2><<<dim3(32, 1), dim3(256), 0, stream>>>(
            c1, 1024, cW2T, AUX + 8192, AUX + 8320, decH, 128, 1024, 120, INZ);
        k_gemm_bt<4><<<dim3(16, 8), dim3(256), 0, stream>>>(
            ctxIn + (size_t)2048*1152, 1152, cW1T, AUX + 6144, AUX + 7168, c1, 1024, 1152, 1024, (const u16*)nullptr);
        k_gemm_bt<2><<<dim3(32, 1), dim3(256), 0, stream>>>(
            c1, 1024, cW2T, AUX + 8192, AUX + 8320, decH + (size_t)2048*128, 128, 1024, 120, INZ + (size_t)2048*8);
    }
    k_decoder<<<dim3(256), dim3(256), 0, stream>>>(
        decH, decF, SM + SM_DNB, SM + SM_DEW, SM + SM_DEB,
        SM + SM_H2W, SM + SM_H2B, IR, IS, flag, d_out);
}

// Round 11
// 435.918 us; speedup vs baseline: 1.1598x; 1.0052x over previous
//
#include <hip/hip_runtime.h>

typedef __attribute__((ext_vector_type(8))) short v8s;
typedef __attribute__((ext_vector_type(4))) float v4f;
typedef unsigned short u16;

#define DINL static __device__ __forceinline__

DINL float b2f(u16 u){ union { unsigned uu; float ff; } x; x.uu = ((unsigned)u)<<16; return x.ff; }
DINL u16 f2b(float f){ union { float ff; unsigned uu; } x; x.ff = f; unsigned r = x.uu + 0x7FFFu + ((x.uu>>16)&1u); return (u16)(r>>16); }
DINL u16 f2b_hu(float f){ union { float ff; unsigned uu; } x; x.ff = f; return (u16)((x.uu + 0x8000u)>>16); }
DINL float sigm(float x){ return 1.0f/(1.0f+__expf(-x)); }
DINL float tanh_(float x){ return 2.0f/(1.0f+__expf(-2.0f*x)) - 1.0f; }
DINL float ld(const void* p, int i, int isf){
    return isf ? ((const float*)p)[i] : b2f(((const u16*)p)[i]);
}
DINL void g2lds16(const u16* g, u16* l){
    __builtin_amdgcn_global_load_lds(
        (const __attribute__((address_space(1))) unsigned int*)g,
        (__attribute__((address_space(3))) unsigned int*)l, 16, 0, 0);
}
DINL int detect_isf(const void* obs_speed){
    const u16* p = (const u16*)obs_speed;
    int f = 0;
    for (int i = 0; i < 16; ++i){
        u16 v = p[2*i];
        if ((v & 0x8000u) || v > 0x3F80u) f = 1;
    }
    return f;
}

// ---- workspace byte offsets ----
#define FLAG_OFF 0x000000
#define AUX_OFF  0x000100
#define ENCF_OFF 0x010000
#define DECF_OFF 0x020000
#define CW2T_OFF 0x050000
#define W2T_OFF  0x090000   // dead after k_pool; decH overlays
#define DECH_OFF 0x090000
#define CW1T_OFF 0x190000
#define IT_OFF   0x3D0000
#define IR_OFF   0x3F0000
#define IS_OFF   0x410000
#define INZ_OFF  0x420000
#define IW1H_OFF 0x430000
#define SM_OFF   0x440000
#define CTX_OFF  0x450000   // ctx_in 4096x1152 bf16
#define AV_OFF   0xD50000   // Avec bf16 (dead after k_pool); c1 overlays
#define BIG_NEED 0x1550000  // AV_OFF + 8MB single-pass c1

#define SM_EEW 0
#define SM_EEB 128
#define SM_ENB 192
#define SM_DEW 448
#define SM_DEB 640
#define SM_DNB 704
#define SM_H2W 1216
#define SM_H2B 1472
#define SM_SEW 1536
#define SM_SEB 2048

// ---------------- unified prep kernel ----------------
DINL void trans_tile(const void* in, u16* out, int K, int N, int isf,
                     int bx, int by, int t, float tile[64][65])
{
    const int nbase = bx*64, kbase = by*64;
    const int c = t & 63, r0 = (t >> 6)*16;
    for (int rep = 0; rep < 16; ++rep){
        int r = r0 + rep;
        int n = nbase + c;
        float v = 0.f;
        if (n < N) v = ld(in, (kbase + r)*N + n, isf);
        tile[r][c] = v;
    }
    __syncthreads();
    for (int rep = 0; rep < 16; ++rep){
        int r = r0 + rep;
        out[(size_t)(nbase + r)*K + kbase + c] = f2b(tile[c][r]);
    }
}

__global__ __launch_bounds__(256) void k_prep(
    const void* obs_traj, const void* obs_rel, const void* obs_speed, const void* noise,
    const void* eeW, const void* eeB, const void* enc_Wih, const void* enc_Whh, const void* encB,
    const void* spW, const void* spB, const void* spdW, const void* spdB,
    const void* pool_l1_W, const void* l1B, const void* bn1g, const void* bn1b,
    const void* pool_l2_W, const void* l2b, const void* bn2g, const void* bn2b,
    const void* seW, const void* seB,
    const void* ctx_l1_W, const void* c1b, const void* cbn1g, const void* cbn1b,
    const void* ctx_l2_W, const void* c2b, const void* cbn2g, const void* cbn2b,
    const void* deW, const void* deB, const void* dec_Wih, const void* dec_Whh, const void* decB,
    const void* h2W, const void* h2B,
    int* flag, float* AUX,
    u16* IT, u16* IR, u16* IS, u16* INZ, u16* IW1H, u16* SM,
    u16* W2T, u16* cW1T, u16* cW2T, u16* encF, u16* decF)
{
    __shared__ float tile[64][65];
    __shared__ int sisf;
    const int t = threadIdx.x;
    if (t == 0){
        int f = detect_isf(obs_speed);
        sisf = f;
        if (blockIdx.x == 0) *flag = f;
    }
    __syncthreads();
    const int isf = sisf;
    int bid = blockIdx.x;
    if (bid < 905){
        int idx = bid*256 + t;
        if (idx < 65536){ IT[idx] = f2b(ld(obs_traj, idx, isf)); return; }
        idx -= 65536;
        if (idx < 65536){ IR[idx] = f2b(ld(obs_rel, idx, isf)); return; }
        idx -= 65536;
        if (idx < 32768){ IS[idx] = f2b(ld(obs_speed, idx, isf)); return; }
        idx -= 32768;
        if (idx < 32768){ INZ[idx] = f2b(ld(noise, idx, isf)); return; }
        idx -= 32768;
        if (idx < 32768){ IW1H[idx] = f2b(ld(pool_l1_W, idx + 32768, isf)); return; }
        idx -= 32768;
        if (idx < 128){ SM[SM_EEW + idx] = f2b(ld(eeW, idx, isf)); return; }
        idx -= 128;
        if (idx < 64){ SM[SM_EEB + idx] = f2b(ld(eeB, idx, isf)); return; }
        idx -= 64;
        if (idx < 256){ SM[SM_ENB + idx] = f2b(ld(encB, idx, isf)); return; }
        idx -= 256;
        if (idx < 192){ SM[SM_DEW + idx] = f2b(ld(deW, idx, isf)); return; }
        idx -= 192;
        if (idx < 64){ SM[SM_DEB + idx] = f2b(ld(deB, idx, isf)); return; }
        idx -= 64;
        if (idx < 512){ SM[SM_DNB + idx] = f2b(ld(decB, idx, isf)); return; }
        idx -= 512;
        if (idx < 256){ SM[SM_H2W + idx] = f2b(ld(h2W, idx, isf)); return; }
        idx -= 256;
        if (idx < 2){ SM[SM_H2B + idx] = f2b(ld(h2B, idx, isf)); return; }
        idx -= 2;
        if (idx < 512){ SM[SM_SEW + idx] = f2b(ld(seW, idx, isf)); return; }
        idx -= 512;
        if (idx < 64){ SM[SM_SEB + idx] = f2b(ld(seB, idx, isf)); return; }
        return;
    }
    bid -= 905;
    if (bid < 512){
        int idx = bid*256 + t;
        if (idx < 32768){
            int jj = idx&7, lane = (idx>>3)&63, kcnf = idx>>9;
            int kc = kcnf&3, nf = kcnf>>2;
            int k = kc*32 + (lane>>4)*8 + jj, n = nf*16 + (lane&15);
            encF[idx] = (k < 64) ? f2b(ld(enc_Wih, k*256+n, isf)) : f2b(ld(enc_Whh, (k-64)*256+n, isf));
        } else {
            idx -= 32768;
            int jj = idx&7, lane = (idx>>3)&63, kcnf = idx>>9;
            int kc = kcnf % 6, nf = kcnf / 6;
            int k = kc*32 + (lane>>4)*8 + jj, n = nf*16 + (lane&15);
            decF[idx] = (k < 64) ? f2b(ld(dec_Wih, k*512+n, isf)) : f2b(ld(dec_Whh, (k-64)*512+n, isf));
        }
        return;
    }
    bid -= 512;
    if (bid < 128){ trans_tile(pool_l2_W, W2T, 512, 1024, isf, bid & 15, bid >> 4, t, tile); return; }
    bid -= 128;
    if (bid < 288){ trans_tile(ctx_l1_W, cW1T, 1152, 1024, isf, bid & 15, bid >> 4, t, tile); return; }
    bid -= 288;
    if (bid < 32){ trans_tile(ctx_l2_W, cW2T, 1024, 120, isf, bid & 1, bid >> 1, t, tile); return; }
    bid -= 32;
    {
        int idx = bid*256 + t;
        if (idx < 512){
            int c = idx;
            float m0 = 0.f, m1 = 0.f, qv = 0.f, cv = 0.f;
            for (int e = 0; e < 64; ++e){
                float w1a = ld(pool_l1_W, e*512 + c, isf);
                m0 += ld(spW, e, isf)*w1a;
                m1 += ld(spW, 64+e, isf)*w1a;
                cv += ld(spB, e, isf)*w1a;
                float w1c = ld(pool_l1_W, (128+e)*512 + c, isf);
                qv += ld(spdW, e, isf)*w1c;
                cv += ld(spdB, e, isf)*w1c;
            }
            cv += ld(l1B, c, isf);
            float g1 = ld(bn1g, c, isf), bb1 = ld(bn1b, c, isf);
            AUX[c] = m0; AUX[512+c] = m1; AUX[1024+c] = qv; AUX[1536+c] = cv;
            AUX[2048+c] = g1; AUX[2560+c] = bb1;
            AUX[3072+c] = g1*m0; AUX[3584+c] = g1*m1;
            return;
        }
        idx -= 512;
        if (idx < 1024){
            float g = ld(bn2g, idx, isf);
            AUX[4096+idx] = g; AUX[5120+idx] = ld(l2b, idx, isf)*g + ld(bn2b, idx, isf);
            return;
        }
        idx -= 1024;
        if (idx < 1024){
            float g = ld(cbn1g, idx, isf);
            AUX[6144+idx] = g; AUX[7168+idx] = ld(c1b, idx, isf)*g + ld(cbn1b, idx, isf);
            return;
        }
        idx -= 1024;
        if (idx < 128){
            int c = idx;
            float g  = (c < 120) ? ld(cbn2g, c, isf) : 1.f;
            float bb = (c < 120) ? (ld(c2b, c, isf)*g + ld(cbn2b, c, isf)) : 0.f;
            AUX[8192+c] = g; AUX[8320+c] = bb;
        }
    }
}

// ---------------- encoder LSTM (16 peds/block) + fused Avec + speed-context ----------------
__global__ __launch_bounds__(256) void k_encoder(
    const u16* __restrict__ rel, const u16* __restrict__ embW, const u16* __restrict__ embB,
    const u16* __restrict__ encF, const u16* __restrict__ encB,
    const u16* __restrict__ IT, const u16* __restrict__ IS, const u16* __restrict__ IW1H,
    const u16* __restrict__ sW, const u16* __restrict__ sB,
    const float* __restrict__ AUX,
    u16* __restrict__ ctxIn, u16* __restrict__ Avec)
{
    __shared__ __align__(16) u16 Als[16*136];
    __shared__ float pxs[16], pys[16], sps[16];
    const int t = threadIdx.x, pedbase = blockIdx.x*16;
    const int w = t>>6, lane = t&63, quad = lane>>4, l15 = lane&15;
    for (int idx = t; idx < 16*64; idx += 256){ int p = idx>>6, jj = idx&63; Als[p*136 + 64 + jj] = 0; }
    if (t < 16){
        pxs[t] = b2f(IT[7*8192 + (pedbase+t)*2 + 0]);
        pys[t] = b2f(IT[7*8192 + (pedbase+t)*2 + 1]);
        sps[t] = b2f(IS[7*4096 + pedbase + t]);
    }
    {
        int p = t>>4, e0 = (t&15)*4;
        float rx = b2f(rel[(pedbase+p)*2 + 0]);
        float ry = b2f(rel[(pedbase+p)*2 + 1]);
        for (int e = e0; e < e0+4; ++e)
            Als[p*136 + e] = f2b(rx*b2f(embW[e]) + ry*b2f(embW[64+e]) + b2f(embB[e]));
    }
    const int j = w*16 + l15;
    const float bi = b2f(encB[j]), bff = b2f(encB[64+j]), bg = b2f(encB[128+j]), bo = b2f(encB[192+j]);
    float c4[4] = {0.f,0.f,0.f,0.f};
    for (int step = 0; step < 8; ++step){
        __syncthreads();
        v4f acc[4];
        for (int q = 0; q < 4; ++q) acc[q] = (v4f){0.f,0.f,0.f,0.f};
        for (int kc = 0; kc < 4; ++kc){
            v8s a = *(const v8s*)&Als[l15*136 + kc*32 + quad*8];
            for (int q = 0; q < 4; ++q){
                int nf = q*4 + w;
                v8s b = *(const v8s*)&encF[((nf*4 + kc)*64 + lane)*8];
                acc[q] = __builtin_amdgcn_mfma_f32_16x16x32_bf16(a, b, acc[q], 0, 0, 0);
            }
        }
        __syncthreads();
        for (int r = 0; r < 4; ++r){
            float gi = sigm(acc[0][r] + bi), gf = sigm(acc[1][r] + bff);
            float gg = tanh_(acc[2][r] + bg), go = sigm(acc[3][r] + bo);
            c4[r] = gf*c4[r] + gi*gg;
            Als[(quad*4 + r)*136 + 64 + j] = f2b(go*tanh_(c4[r]));
        }
        if (step < 7){
            int p = t>>4, e0 = (t&15)*4;
            float rx = b2f(rel[(step+1)*8192 + (pedbase+p)*2 + 0]);
            float ry = b2f(rel[(step+1)*8192 + (pedbase+p)*2 + 1]);
            for (int e = e0; e < e0+4; ++e)
                Als[p*136 + e] = f2b(rx*b2f(embW[e]) + ry*b2f(embW[64+e]) + b2f(embB[e]));
        }
    }
    __syncthreads();
    for (int idx = t; idx < 1024; idx += 256){
        int p = idx>>6, e = idx&63;
        ctxIn[(size_t)(pedbase+p)*1152 + e] = Als[p*136 + 64 + e];
    }
    {
        const int c0 = (t&127)*4, pg = (t>>7)*8;
        float4 acc[8];
        for (int p = 0; p < 8; ++p) acc[p] = make_float4(0.f,0.f,0.f,0.f);
        for (int e = 0; e < 64; ++e){
            ushort4 wv = *(const ushort4*)(IW1H + e*512 + c0);
            float w0 = b2f(wv.x), w1 = b2f(wv.y), w2 = b2f(wv.z), w3 = b2f(wv.w);
            for (int p = 0; p < 8; ++p){
                float h = b2f(Als[(pg+p)*136 + 64 + e]);
                acc[p].x += h*w0; acc[p].y += h*w1; acc[p].z += h*w2; acc[p].w += h*w3;
            }
        }
        float4 m0 = *(const float4*)(AUX + c0),        m1 = *(const float4*)(AUX + 512 + c0);
        float4 qv = *(const float4*)(AUX + 1024 + c0), cv = *(const float4*)(AUX + 1536 + c0);
        float4 g1 = *(const float4*)(AUX + 2048 + c0), bb = *(const float4*)(AUX + 2560 + c0);
        for (int p = 0; p < 8; ++p){
            float px = pxs[pg+p], py = pys[pg+p], sp = sps[pg+p];
            ushort4 o;
            o.x = f2b(g1.x*(px*m0.x + py*m1.x + sp*qv.x + cv.x + acc[p].x) + bb.x);
            o.y = f2b(g1.y*(px*m0.y + py*m1.y + sp*qv.y + cv.y + acc[p].y) + bb.y);
            o.z = f2b(g1.z*(px*m0.z + py*m1.z + sp*qv.z + cv.z + acc[p].z) + bb.z);
            o.w = f2b(g1.w*(px*m0.w + py*m1.w + sp*qv.w + cv.w + acc[p].w) + bb.w);
            *(ushort4*)&Avec[(size_t)(pedbase+pg+p)*512 + c0] = o;
        }
    }
    {
        int s = t & 63;
        for (int rep = 0; rep < 4; ++rep){
            int p = (t>>6)*4 + rep;
            int nid = pedbase + p;
            float a = b2f(sB[s]);
            for (int tt = 0; tt < 8; ++tt) a += b2f(IS[tt*4096 + nid]) * b2f(sW[tt*64 + s]);
            ctxIn[(size_t)nid*1152 + 1088 + s] = f2b(sigm(a));
        }
    }
}

// ---------------- pool GEMM v8: v4 structure + cheap A-build ----------------
// pm[il][k] = pos_il . M precomputed once per block in LDS (build: 1 sub/elem);
// bf16 pair-packing via v_perm (bit-identical half-up rounding).
__global__ __launch_bounds__(256, 3) void k_pool(
    const u16* __restrict__ Avec, const u16* __restrict__ W2T,
    const u16* __restrict__ IT, const float* __restrict__ AUX,
    u16* __restrict__ ctxIn)
{
    __shared__ __align__(16) u16 Als[64*72];      // A-tile, pad-72 (16B rows)
    __shared__ __align__(16) u16 Bls[256*64];     // B-tile, XOR-swizzled granules
    __shared__ __align__(16) float pmls[1024];    // pm[2][512]
    const int t = threadIdx.x;
    const int g = blockIdx.x >> 4, ip = blockIdx.x & 15;
    const int n0 = blockIdx.y * 256;
    const int w = t>>6, lane = t&63, quad = lane>>4, l15 = lane&15;
    const int aj = t>>3, ao = t&7;
    // wave-uniform anchor positions (broadcast loads)
    const float px0 = b2f(IT[7*8192 + (g*32 + ip*2 + 0)*2 + 0]);
    const float py0 = b2f(IT[7*8192 + (g*32 + ip*2 + 0)*2 + 1]);
    const float px1 = b2f(IT[7*8192 + (g*32 + ip*2 + 1)*2 + 0]);
    const float py1 = b2f(IT[7*8192 + (g*32 + ip*2 + 1)*2 + 1]);
    for (int i = t; i < 512; i += 256){
        float m0 = AUX[3072 + i], m1 = AUX[3584 + i];
        pmls[i]       = px0*m0 + py0*m1;
        pmls[512 + i] = px1*m0 + py1*m1;
    }
    const u16* bsrc = W2T + (size_t)(n0 + w*8 + (lane>>3))*512 + (size_t)(((lane&7) ^ (lane>>3)))*8;
    u16* bdst = &Bls[w*512];
    const u16* arow = Avec + (size_t)(g*32+aj)*512 + ao*8;
    v4f acc[4][4];
    for (int mf = 0; mf < 4; ++mf) for (int nf = 0; nf < 4; ++nf) acc[mf][nf] = (v4f){0.f,0.f,0.f,0.f};
    union { v8s v; u16 u[8]; } av;
    av.v = *(const v8s*)arow;                      // prefetch chunk 0
    for (int ch = 0; ch < 8; ++ch){
        const int k0 = ch*64;
        __syncthreads();                           // also covers pmls for ch=0
        for (int it = 0; it < 8; ++it)
            g2lds16(bsrc + k0 + it*16384, bdst + it*2048);
        {   // A build: 1 sub + 1 max + 1 add per elem + 1 perm per pair
            float a0[8];
            #pragma unroll
            for (int i = 0; i < 8; ++i) a0[i] = b2f(av.u[i]);
            #pragma unroll
            for (int il = 0; il < 2; ++il){
                float4 p0 = *(const float4*)&pmls[il*512 + k0 + ao*8];
                float4 p1 = *(const float4*)&pmls[il*512 + k0 + ao*8 + 4];
                float pmv[8] = {p0.x,p0.y,p0.z,p0.w,p1.x,p1.y,p1.z,p1.w};
                union { unsigned u[4]; v8s v; } pk;
                #pragma unroll
                for (int jj = 0; jj < 4; ++jj){
                    union { float f; unsigned u; } x0, x1;
                    x0.f = fmaxf(a0[2*jj]   - pmv[2*jj],   0.f);
                    x1.f = fmaxf(a0[2*jj+1] - pmv[2*jj+1], 0.f);
                    pk.u[jj] = __builtin_amdgcn_perm(x1.u + 0x8000u, x0.u + 0x8000u, 0x07060302u);
                }
                *(v8s*)&Als[(il*32+aj)*72 + ao*8] = pk.v;
            }
        }
        if (ch < 7) av.v = *(const v8s*)(arow + (ch+1)*64);   // prefetch next
        __syncthreads();
        for (int kc = 0; kc < 2; ++kc){
            v8s af[4];
            for (int mf = 0; mf < 4; ++mf)
                af[mf] = *(const v8s*)&Als[(mf*16 + l15)*72 + kc*32 + quad*8];
            const int sl = ((kc*4 + quad) ^ (l15&7))*8;
            #pragma unroll
            for (int nf = 0; nf < 4; ++nf){
                v8s bf = *(const v8s*)&Bls[(w*64 + nf*16 + l15)*64 + sl];
                acc[0][nf] = __builtin_amdgcn_mfma_f32_16x16x32_bf16(af[0], bf, acc[0][nf], 0, 0, 0);
                acc[1][nf] = __builtin_amdgcn_mfma_f32_16x16x32_bf16(af[1], bf, acc[1][nf], 0, 0, 0);
                acc[2][nf] = __builtin_amdgcn_mfma_f32_16x16x32_bf16(af[2], bf, acc[2][nf], 0, 0, 0);
                acc[3][nf] = __builtin_amdgcn_mfma_f32_16x16x32_bf16(af[3], bf, acc[3][nf], 0, 0, 0);
            }
        }
    }
    const float* S2 = AUX + 4096; const float* B2 = AUX + 5120;
    for (int nf = 0; nf < 4; ++nf){
        int n = n0 + w*64 + nf*16 + l15;
        float s = S2[n], bb = B2[n];
        float mm0 = 0.f, mm1 = 0.f;
        for (int mf = 0; mf < 2; ++mf) for (int r = 0; r < 4; ++r) mm0 = fmaxf(mm0, fmaxf(s*acc[mf][nf][r] + bb, 0.f));
        for (int mf = 2; mf < 4; ++mf) for (int r = 0; r < 4; ++r) mm1 = fmaxf(mm1, fmaxf(s*acc[mf][nf][r] + bb, 0.f));
        mm0 = fmaxf(mm0, __shfl_xor(mm0, 16)); mm0 = fmaxf(mm0, __shfl_xor(mm0, 32));
        mm1 = fmaxf(mm1, __shfl_xor(mm1, 16)); mm1 = fmaxf(mm1, __shfl_xor(mm1, 32));
        if (quad == 0) ctxIn[(size_t)(g*32 + ip*2 + 0)*1152 + 64 + n] = f2b(mm0);
        if (quad == 1) ctxIn[(size_t)(g*32 + ip*2 + 1)*1152 + 64 + n] = f2b(mm1);
    }
}

// ---------------- generic MFMA GEMM, M-tile = MF*32: out = relu(S[n]*A@BT' + Bb[n]) ----------------
template<int MF>
__global__ __launch_bounds__(256) void k_gemm_bt(
    const u16* __restrict__ A, int lda, const u16* __restrict__ BT,
    const float* __restrict__ S, const float* __restrict__ Bb,
    u16* __restrict__ out, int ldo, int K, int validN,
    const u16* __restrict__ noisep)
{
    __shared__ __align__(16) u16 Als[MF*32*72];
    __shared__ __align__(16) u16 Bls[128*72];
    const int t = threadIdx.x;
    const int m0 = blockIdx.x*(MF*32), n0 = blockIdx.y*128;
    const int w = t>>6, lane = t&63, quad = lane>>4, l15 = lane&15;
    const int rw = w>>1, cw = w&1;
    v4f acc[MF][4];
    for (int mf = 0; mf < MF; ++mf) for (int nf = 0; nf < 4; ++nf) acc[mf][nf] = (v4f){0.f,0.f,0.f,0.f};
    const int nch = K >> 6;
    for (int ch = 0; ch < nch; ++ch){
        const int k0 = ch*64;
        __syncthreads();
        if (MF == 4){
            const int srow = t>>1, sh = t&1;
            const u16* srcA = A + (size_t)(m0+srow)*lda + k0 + sh*32;
            u16* dstA = &Als[srow*72 + sh*32];
            ((v8s*)dstA)[0] = ((const v8s*)srcA)[0];
            ((v8s*)dstA)[1] = ((const v8s*)srcA)[1];
            ((v8s*)dstA)[2] = ((const v8s*)srcA)[2];
            ((v8s*)dstA)[3] = ((const v8s*)srcA)[3];
        } else {
            const int srow = t>>2, sh = t&3;
            const u16* srcA = A + (size_t)(m0+srow)*lda + k0 + sh*16;
            u16* dstA = &Als[srow*72 + sh*16];
            ((v8s*)dstA)[0] = ((const v8s*)srcA)[0];
            ((v8s*)dstA)[1] = ((const v8s*)srcA)[1];
        }
        {
            const int srow = t>>1, sh = t&1;
            const u16* srcB = BT + (size_t)(n0+srow)*K + k0 + sh*32;
            u16* dstB = &Bls[srow*72 + sh*32];
            ((v8s*)dstB)[0] = ((const v8s*)srcB)[0];
            ((v8s*)dstB)[1] = ((const v8s*)srcB)[1];
            ((v8s*)dstB)[2] = ((const v8s*)srcB)[2];
            ((v8s*)dstB)[3] = ((const v8s*)srcB)[3];
        }
        __syncthreads();
        for (int kc = 0; kc < 2; ++kc){
            v8s af[MF], bf[4];
            for (int mf = 0; mf < MF; ++mf) af[mf] = *(const v8s*)&Als[(rw*(MF*16) + mf*16 + l15)*72 + kc*32 + quad*8];
            for (int nf = 0; nf < 4; ++nf) bf[nf] = *(const v8s*)&Bls[(cw*64 + nf*16 + l15)*72 + kc*32 + quad*8];
            for (int mf = 0; mf < MF; ++mf)
                for (int nf = 0; nf < 4; ++nf)
                    acc[mf][nf] = __builtin_amdgcn_mfma_f32_16x16x32_bf16(af[mf], bf[nf], acc[mf][nf], 0, 0, 0);
        }
    }
    for (int nf = 0; nf < 4; ++nf){
        int n = n0 + cw*64 + nf*16 + l15;
        bool okn = (n < validN);
        float s = okn ? S[n] : 0.f, bb = okn ? Bb[n] : 0.f;
        bool okz = (!okn) && (noisep != nullptr) && (n < 128);
        for (int mf = 0; mf < MF; ++mf){
            int m = m0 + rw*(MF*16) + mf*16 + quad*4;
            for (int r = 0; r < 4; ++r){
                float v = fmaxf(s*acc[mf][nf][r] + bb, 0.f);
                if (okn) out[(size_t)(m+r)*ldo + n] = f2b(v);
                else if (okz) out[(size_t)(m+r)*ldo + n] = noisep[(size_t)(m+r)*8 + (n - 120)];
            }
        }
    }
}

// ---------------- decoder LSTM rollout ----------------
__global__ __launch_bounds__(256) void k_decoder(
    const u16* __restrict__ decH0, const u16* __restrict__ decF, const u16* __restrict__ decB,
    const u16* __restrict__ dembW, const u16* __restrict__ dembB,
    const u16* __restrict__ h2pW, const u16* __restrict__ h2pB,
    const u16* __restrict__ obs_rel, const u16* __restrict__ obs_speed,
    const int* __restrict__ flag, void* __restrict__ outp)
{
    __shared__ __align__(16) u16 Als[16*200];
    __shared__ float rps[16][2];
    __shared__ float sps[16];
    __shared__ float h2ps[256];
    const int t = threadIdx.x, pedbase = blockIdx.x*16;
    const int w = t>>6, lane = t&63, quad = lane>>4, l15 = lane&15;
    const int isf = *flag;
    for (int idx = t; idx < 2048; idx += 256){
        int p = idx>>7, jj = idx&127;
        Als[p*200 + 64 + jj] = decH0[(pedbase+p)*128 + jj];
    }
    h2ps[t] = b2f(h2pW[t]);
    if (t < 16) sps[t] = b2f(obs_speed[7*4096 + pedbase + t]);
    if (t < 32){ int p = t>>1, cmp = t&1; rps[p][cmp] = b2f(obs_rel[7*8192 + (pedbase+p)*2 + cmp]); }
    __syncthreads();
    {
        int p = t>>4, e0 = (t&15)*4;
        for (int e = e0; e < e0+4; ++e){
            float v = rps[p][0]*b2f(dembW[e]) + rps[p][1]*b2f(dembW[64+e]) + sps[p]*b2f(dembW[128+e]) + b2f(dembB[e]);
            Als[p*200 + e] = f2b(v);
        }
    }
    float bI[2], bF[2], bG[2], bO[2];
    for (int nfl = 0; nfl < 2; ++nfl){
        int j = w*32 + nfl*16 + l15;
        bI[nfl] = b2f(decB[j]); bF[nfl] = b2f(decB[128+j]);
        bG[nfl] = b2f(decB[256+j]); bO[nfl] = b2f(decB[384+j]);
    }
    float c8[2][4] = {{0.f,0.f,0.f,0.f},{0.f,0.f,0.f,0.f}};
    for (int s = 0; s < 12; ++s){
        __syncthreads();
        v4f acc[4][2];
        for (int q = 0; q < 4; ++q) for (int nfl = 0; nfl < 2; ++nfl) acc[q][nfl] = (v4f){0.f,0.f,0.f,0.f};
        for (int kc = 0; kc < 6; ++kc){
            v8s a = *(const v8s*)&Als[l15*200 + kc*32 + quad*8];
            for (int q = 0; q < 4; ++q){
                for (int nfl = 0; nfl < 2; ++nfl){
                    int nf = q*8 + w*2 + nfl;
                    v8s b = *(const v8s*)&decF[((nf*6 + kc)*64 + lane)*8];
                    acc[q][nfl] = __builtin_amdgcn_mfma_f32_16x16x32_bf16(a, b, acc[q][nfl], 0, 0, 0);
                }
            }
        }
        __syncthreads();
        for (int nfl = 0; nfl < 2; ++nfl){
            int j = w*32 + nfl*16 + l15;
            for (int r = 0; r < 4; ++r){
                float gi = sigm(acc[0][nfl][r] + bI[nfl]), gf = sigm(acc[1][nfl][r] + bF[nfl]);
                float gg = tanh_(acc[2][nfl][r] + bG[nfl]), go = sigm(acc[3][nfl][r] + bO[nfl]);
                c8[nfl][r] = gf*c8[nfl][r] + gi*gg;
                Als[(quad*4 + r)*200 + 64 + j] = f2b(go*tanh_(c8[nfl][r]));
            }
        }
        __syncthreads();
        {
            int p = t>>4, cmp = (t>>3)&1, part = t&7;
            float rp = 0.f;
            int j0 = part*16;
            for (int jj = j0; jj < j0+16; ++jj)
                rp += b2f(Als[p*200 + 64 + jj]) * h2ps[jj*2 + cmp];
            rp += __shfl_xor(rp, 1);
            rp += __shfl_xor(rp, 2);
            rp += __shfl_xor(rp, 4);
            if (part == 0){
                rp += b2f(h2pB[cmp]);
                int oi = s*8192 + (pedbase+p)*2 + cmp;
                if (isf) ((float*)outp)[oi] = rp;
                else     ((u16*)outp)[oi]   = f2b(rp);
                rps[p][cmp] = rp;
            }
        }
        __syncthreads();
        {
            int p = t>>4, e0 = (t&15)*4;
            for (int e = e0; e < e0+4; ++e){
                float v = rps[p][0]*b2f(dembW[e]) + rps[p][1]*b2f(dembW[64+e]) + sps[p]*b2f(dembW[128+e]) + b2f(dembB[e]);
                Als[p*200 + e] = f2b(v);
            }
        }
    }
}

extern "C" void kernel_launch(void* const* d_in, const int* in_sizes, int n_in,
                              void* d_out, int out_size, void* d_ws, size_t ws_size,
                              hipStream_t stream)
{
    (void)in_sizes; (void)n_in; (void)out_size;
    const void* obs_traj  = d_in[0];
    const void* obs_rel   = d_in[1];
    const void* obs_speed = d_in[2];
    const void* noise     = d_in[3];
    const void* enc_emb_W = d_in[4];
    const void* enc_emb_b = d_in[5];
    const void* enc_Wih   = d_in[6];
    const void* enc_Whh   = d_in[7];
    const void* enc_b     = d_in[8];
    const void* pool_sp_W = d_in[9];
    const void* pool_sp_b = d_in[10];
    const void* pool_spd_W= d_in[11];
    const void* pool_spd_b= d_in[12];
    const void* pool_l1_W = d_in[13];
    const void* pool_l1_b = d_in[14];
    const void* pool_bn1_g= d_in[15];
    const void* pool_bn1_b= d_in[16];
    const void* pool_l2_W = d_in[17];
    const void* pool_l2_b = d_in[18];
    const void* pool_bn2_g= d_in[19];
    const void* pool_bn2_b= d_in[20];
    const void* spd_emb_W = d_in[21];
    const void* spd_emb_b = d_in[22];
    const void* ctx_l1_W  = d_in[23];
    const void* ctx_l1_b  = d_in[24];
    const void* ctx_bn1_g = d_in[25];
    const void* ctx_bn1_b = d_in[26];
    const void* ctx_l2_W  = d_in[27];
    const void* ctx_l2_b  = d_in[28];
    const void* ctx_bn2_g = d_in[29];
    const void* ctx_bn2_b = d_in[30];
    const void* dec_emb_W = d_in[31];
    const void* dec_emb_b = d_in[32];
    const void* dec_Wih   = d_in[33];
    const void* dec_Whh   = d_in[34];
    const void* dec_b     = d_in[35];
    const void* h2p_W     = d_in[36];
    const void* h2p_b     = d_in[37];

    char* ws = (char*)d_ws;
    int*   flag  = (int*)  (ws + FLAG_OFF);
    float* AUX   = (float*)(ws + AUX_OFF);
    u16*   encF  = (u16*)  (ws + ENCF_OFF);
    u16*   decF  = (u16*)  (ws + DECF_OFF);
    u16*   cW2T  = (u16*)  (ws + CW2T_OFF);
    u16*   W2T   = (u16*)  (ws + W2T_OFF);
    u16*   decH  = (u16*)  (ws + DECH_OFF);
    u16*   cW1T  = (u16*)  (ws + CW1T_OFF);
    u16*   IT    = (u16*)  (ws + IT_OFF);
    u16*   IR    = (u16*)  (ws + IR_OFF);
    u16*   IS    = (u16*)  (ws + IS_OFF);
    u16*   INZ   = (u16*)  (ws + INZ_OFF);
    u16*   IW1H  = (u16*)  (ws + IW1H_OFF);
    u16*   SM    = (u16*)  (ws + SM_OFF);
    u16*   ctxIn = (u16*)  (ws + CTX_OFF);
    u16*   Avec  = (u16*)  (ws + AV_OFF);
    u16*   c1    = (u16*)  (ws + AV_OFF);   // overlays Avec (dead after k_pool)
    const bool big = (ws_size >= (size_t)BIG_NEED);

    k_prep<<<dim3(1876), dim3(256), 0, stream>>>(
        obs_traj, obs_rel, obs_speed, noise,
        enc_emb_W, enc_emb_b, enc_Wih, enc_Whh, enc_b,
        pool_sp_W, pool_sp_b, pool_spd_W, pool_spd_b,
        pool_l1_W, pool_l1_b, pool_bn1_g, pool_bn1_b,
        pool_l2_W, pool_l2_b, pool_bn2_g, pool_bn2_b,
        spd_emb_W, spd_emb_b,
        ctx_l1_W, ctx_l1_b, ctx_bn1_g, ctx_bn1_b,
        ctx_l2_W, ctx_l2_b, ctx_bn2_g, ctx_bn2_b,
        dec_emb_W, dec_emb_b, dec_Wih, dec_Whh, dec_b,
        h2p_W, h2p_b,
        flag, AUX, IT, IR, IS, INZ, IW1H, SM,
        W2T, cW1T, cW2T, encF, decF);
    k_encoder<<<dim3(256), dim3(256), 0, stream>>>(
        IR, SM + SM_EEW, SM + SM_EEB, encF, SM + SM_ENB,
        IT, IS, IW1H, SM + SM_SEW, SM + SM_SEB, AUX, ctxIn, Avec);
    k_pool<<<dim3(2048, 4), dim3(256), 0, stream>>>(Avec, W2T, IT, AUX, ctxIn);
    if (big){
        k_gemm_bt<4><<<dim3(32, 8), dim3(256), 0, stream>>>(
            ctxIn, 1152, cW1T, AUX + 6144, AUX + 7168, c1, 1024, 1152, 1024, (const u16*)nullptr);
        k_gemm_bt<2><<<dim3(64, 1), dim3(256), 0, stream>>>(
            c1, 1024, cW2T, AUX + 8192, AUX + 8320, decH, 128, 1024, 120, INZ);
    } else {
        k_gemm_bt<4><<<dim3(16, 8), dim3(256), 0, stream>>>(
            ctxIn, 1152, cW1T, AUX + 6144, AUX + 7168, c1, 1024, 1152, 1024, (const u16*)nullptr);
        k_gemm_bt<2><<<dim3(32, 1), dim3(256), 0, stream>>>(
            c1, 1024, cW2T, AUX + 8192, AUX + 8320, decH, 128, 1024, 120, INZ);
        k_gemm_bt<4><<<dim3(16, 8), dim3(256), 0, stream>>>(
            ctxIn + (size_t)2048*1152, 1152, cW1T, AUX + 6144, AUX + 7168, c1, 1024, 1152, 1024, (const u16*)nullptr);
        k_gemm_bt<2><<<dim3(32, 1), dim3(256), 0, stream>>>(
            c1, 1024, cW2T, AUX + 8192, AUX + 8320, decH + (size_t)2048*128, 128, 1024, 120, INZ + (size_t)2048*8);
    }
    k_decoder<<<dim3(256), dim3(256), 0, stream>>>(
        decH, decF, SM + SM_DNB, SM + SM_DEW, SM + SM_DEB,
        SM + SM_H2W, SM + SM_H2B, IR, IS, flag, d_out);
}

// Round 12
// 430.516 us; speedup vs baseline: 1.1744x; 1.0125x over previous
//
#include <hip/hip_runtime.h>

typedef __attribute__((ext_vector_type(8))) short v8s;
typedef __attribute__((ext_vector_type(4))) float v4f;
typedef unsigned short u16;

#define DINL static __device__ __forceinline__

DINL float b2f(u16 u){ union { unsigned uu; float ff; } x; x.uu = ((unsigned)u)<<16; return x.ff; }
DINL u16 f2b(float f){ union { float ff; unsigned uu; } x; x.ff = f; unsigned r = x.uu + 0x7FFFu + ((x.uu>>16)&1u); return (u16)(r>>16); }
DINL float sigm(float x){ return 1.0f/(1.0f+__expf(-x)); }
DINL float tanh_(float x){ return 2.0f/(1.0f+__expf(-2.0f*x)) - 1.0f; }
DINL float ld(const void* p, int i, int isf){
    return isf ? ((const float*)p)[i] : b2f(((const u16*)p)[i]);
}
DINL void g2lds16(const u16* g, u16* l){
    __builtin_amdgcn_global_load_lds(
        (const __attribute__((address_space(1))) unsigned int*)g,
        (__attribute__((address_space(3))) unsigned int*)l, 16, 0, 0);
}
DINL int detect_isf(const void* obs_speed){
    const u16* p = (const u16*)obs_speed;
    int f = 0;
    for (int i = 0; i < 16; ++i){
        u16 v = p[2*i];
        if ((v & 0x8000u) || v > 0x3F80u) f = 1;
    }
    return f;
}

// ---- workspace byte offsets ----
#define FLAG_OFF 0x000000
#define AUX_OFF  0x000100
#define ENCF_OFF 0x010000
#define DECF_OFF 0x020000
#define CW2T_OFF 0x050000
#define W2T_OFF  0x090000   // dead after k_pool; decH overlays
#define DECH_OFF 0x090000
#define CW1T_OFF 0x190000
#define IT_OFF   0x3D0000
#define IR_OFF   0x3F0000
#define IS_OFF   0x410000
#define INZ_OFF  0x420000
#define IW1H_OFF 0x430000
#define SM_OFF   0x440000
#define CTX_OFF  0x450000   // ctx_in 4096x1152 bf16
#define AV_OFF   0xD50000   // Avec bf16 (dead after k_pool); c1 overlays
#define BIG_NEED 0x1550000  // AV_OFF + 8MB single-pass c1

#define SM_EEW 0
#define SM_EEB 128
#define SM_ENB 192
#define SM_DEW 448
#define SM_DEB 640
#define SM_DNB 704
#define SM_H2W 1216
#define SM_H2B 1472
#define SM_SEW 1536
#define SM_SEB 2048

// ---------------- unified prep kernel ----------------
DINL void trans_tile(const void* in, u16* out, int K, int N, int isf,
                     int bx, int by, int t, float tile[64][65])
{
    const int nbase = bx*64, kbase = by*64;
    const int c = t & 63, r0 = (t >> 6)*16;
    for (int rep = 0; rep < 16; ++rep){
        int r = r0 + rep;
        int n = nbase + c;
        float v = 0.f;
        if (n < N) v = ld(in, (kbase + r)*N + n, isf);
        tile[r][c] = v;
    }
    __syncthreads();
    for (int rep = 0; rep < 16; ++rep){
        int r = r0 + rep;
        out[(size_t)(nbase + r)*K + kbase + c] = f2b(tile[c][r]);
    }
}

__global__ __launch_bounds__(256) void k_prep(
    const void* obs_traj, const void* obs_rel, const void* obs_speed, const void* noise,
    const void* eeW, const void* eeB, const void* enc_Wih, const void* enc_Whh, const void* encB,
    const void* spW, const void* spB, const void* spdW, const void* spdB,
    const void* pool_l1_W, const void* l1B, const void* bn1g, const void* bn1b,
    const void* pool_l2_W, const void* l2b, const void* bn2g, const void* bn2b,
    const void* seW, const void* seB,
    const void* ctx_l1_W, const void* c1b, const void* cbn1g, const void* cbn1b,
    const void* ctx_l2_W, const void* c2b, const void* cbn2g, const void* cbn2b,
    const void* deW, const void* deB, const void* dec_Wih, const void* dec_Whh, const void* decB,
    const void* h2W, const void* h2B,
    int* flag, float* AUX,
    u16* IT, u16* IR, u16* IS, u16* INZ, u16* IW1H, u16* SM,
    u16* W2T, u16* cW1T, u16* cW2T, u16* encF, u16* decF)
{
    __shared__ float tile[64][65];
    __shared__ int sisf;
    const int t = threadIdx.x;
    if (t == 0){
        int f = detect_isf(obs_speed);
        sisf = f;
        if (blockIdx.x == 0) *flag = f;
    }
    __syncthreads();
    const int isf = sisf;
    int bid = blockIdx.x;
    if (bid < 905){
        int idx = bid*256 + t;
        if (idx < 65536){ IT[idx] = f2b(ld(obs_traj, idx, isf)); return; }
        idx -= 65536;
        if (idx < 65536){ IR[idx] = f2b(ld(obs_rel, idx, isf)); return; }
        idx -= 65536;
        if (idx < 32768){ IS[idx] = f2b(ld(obs_speed, idx, isf)); return; }
        idx -= 32768;
        if (idx < 32768){ INZ[idx] = f2b(ld(noise, idx, isf)); return; }
        idx -= 32768;
        if (idx < 32768){ IW1H[idx] = f2b(ld(pool_l1_W, idx + 32768, isf)); return; }
        idx -= 32768;
        if (idx < 128){ SM[SM_EEW + idx] = f2b(ld(eeW, idx, isf)); return; }
        idx -= 128;
        if (idx < 64){ SM[SM_EEB + idx] = f2b(ld(eeB, idx, isf)); return; }
        idx -= 64;
        if (idx < 256){ SM[SM_ENB + idx] = f2b(ld(encB, idx, isf)); return; }
        idx -= 256;
        if (idx < 192){ SM[SM_DEW + idx] = f2b(ld(deW, idx, isf)); return; }
        idx -= 192;
        if (idx < 64){ SM[SM_DEB + idx] = f2b(ld(deB, idx, isf)); return; }
        idx -= 64;
        if (idx < 512){ SM[SM_DNB + idx] = f2b(ld(decB, idx, isf)); return; }
        idx -= 512;
        if (idx < 256){ SM[SM_H2W + idx] = f2b(ld(h2W, idx, isf)); return; }
        idx -= 256;
        if (idx < 2){ SM[SM_H2B + idx] = f2b(ld(h2B, idx, isf)); return; }
        idx -= 2;
        if (idx < 512){ SM[SM_SEW + idx] = f2b(ld(seW, idx, isf)); return; }
        idx -= 512;
        if (idx < 64){ SM[SM_SEB + idx] = f2b(ld(seB, idx, isf)); return; }
        return;
    }
    bid -= 905;
    if (bid < 512){
        int idx = bid*256 + t;
        if (idx < 32768){
            int jj = idx&7, lane = (idx>>3)&63, kcnf = idx>>9;
            int kc = kcnf&3, nf = kcnf>>2;
            int k = kc*32 + (lane>>4)*8 + jj, n = nf*16 + (lane&15);
            encF[idx] = (k < 64) ? f2b(ld(enc_Wih, k*256+n, isf)) : f2b(ld(enc_Whh, (k-64)*256+n, isf));
        } else {
            idx -= 32768;
            int jj = idx&7, lane = (idx>>3)&63, kcnf = idx>>9;
            int kc = kcnf % 6, nf = kcnf / 6;
            int k = kc*32 + (lane>>4)*8 + jj, n = nf*16 + (lane&15);
            decF[idx] = (k < 64) ? f2b(ld(dec_Wih, k*512+n, isf)) : f2b(ld(dec_Whh, (k-64)*512+n, isf));
        }
        return;
    }
    bid -= 512;
    if (bid < 128){ trans_tile(pool_l2_W, W2T, 512, 1024, isf, bid & 15, bid >> 4, t, tile); return; }
    bid -= 128;
    if (bid < 288){ trans_tile(ctx_l1_W, cW1T, 1152, 1024, isf, bid & 15, bid >> 4, t, tile); return; }
    bid -= 288;
    if (bid < 32){ trans_tile(ctx_l2_W, cW2T, 1024, 120, isf, bid & 1, bid >> 1, t, tile); return; }
    bid -= 32;
    {
        int idx = bid*256 + t;
        if (idx < 512){
            int c = idx;
            float m0 = 0.f, m1 = 0.f, qv = 0.f, cv = 0.f;
            for (int e = 0; e < 64; ++e){
                float w1a = ld(pool_l1_W, e*512 + c, isf);
                m0 += ld(spW, e, isf)*w1a;
                m1 += ld(spW, 64+e, isf)*w1a;
                cv += ld(spB, e, isf)*w1a;
                float w1c = ld(pool_l1_W, (128+e)*512 + c, isf);
                qv += ld(spdW, e, isf)*w1c;
                cv += ld(spdB, e, isf)*w1c;
            }
            cv += ld(l1B, c, isf);
            float g1 = ld(bn1g, c, isf), bb1 = ld(bn1b, c, isf);
            AUX[c] = m0; AUX[512+c] = m1; AUX[1024+c] = qv; AUX[1536+c] = cv;
            AUX[2048+c] = g1; AUX[2560+c] = bb1;
            AUX[3072+c] = g1*m0; AUX[3584+c] = g1*m1;
            return;
        }
        idx -= 512;
        if (idx < 1024){
            float g = ld(bn2g, idx, isf);
            AUX[4096+idx] = g; AUX[5120+idx] = ld(l2b, idx, isf)*g + ld(bn2b, idx, isf);
            return;
        }
        idx -= 1024;
        if (idx < 1024){
            float g = ld(cbn1g, idx, isf);
            AUX[6144+idx] = g; AUX[7168+idx] = ld(c1b, idx, isf)*g + ld(cbn1b, idx, isf);
            return;
        }
        idx -= 1024;
        if (idx < 128){
            int c = idx;
            float g  = (c < 120) ? ld(cbn2g, c, isf) : 1.f;
            float bb = (c < 120) ? (ld(c2b, c, isf)*g + ld(cbn2b, c, isf)) : 0.f;
            AUX[8192+c] = g; AUX[8320+c] = bb;
        }
    }
}

// ---------------- encoder LSTM (16 peds/block) + fused Avec + speed-context ----------------
__global__ __launch_bounds__(256) void k_encoder(
    const u16* __restrict__ rel, const u16* __restrict__ embW, const u16* __restrict__ embB,
    const u16* __restrict__ encF, const u16* __restrict__ encB,
    const u16* __restrict__ IT, const u16* __restrict__ IS, const u16* __restrict__ IW1H,
    const u16* __restrict__ sW, const u16* __restrict__ sB,
    const float* __restrict__ AUX,
    u16* __restrict__ ctxIn, u16* __restrict__ Avec)
{
    __shared__ __align__(16) u16 Als[16*136];
    __shared__ float pxs[16], pys[16], sps[16];
    const int t = threadIdx.x, pedbase = blockIdx.x*16;
    const int w = t>>6, lane = t&63, quad = lane>>4, l15 = lane&15;
    for (int idx = t; idx < 16*64; idx += 256){ int p = idx>>6, jj = idx&63; Als[p*136 + 64 + jj] = 0; }
    if (t < 16){
        pxs[t] = b2f(IT[7*8192 + (pedbase+t)*2 + 0]);
        pys[t] = b2f(IT[7*8192 + (pedbase+t)*2 + 1]);
        sps[t] = b2f(IS[7*4096 + pedbase + t]);
    }
    {
        int p = t>>4, e0 = (t&15)*4;
        float rx = b2f(rel[(pedbase+p)*2 + 0]);
        float ry = b2f(rel[(pedbase+p)*2 + 1]);
        for (int e = e0; e < e0+4; ++e)
            Als[p*136 + e] = f2b(rx*b2f(embW[e]) + ry*b2f(embW[64+e]) + b2f(embB[e]));
    }
    const int j = w*16 + l15;
    const float bi = b2f(encB[j]), bff = b2f(encB[64+j]), bg = b2f(encB[128+j]), bo = b2f(encB[192+j]);
    float c4[4] = {0.f,0.f,0.f,0.f};
    for (int step = 0; step < 8; ++step){
        __syncthreads();
        v4f acc[4];
        for (int q = 0; q < 4; ++q) acc[q] = (v4f){0.f,0.f,0.f,0.f};
        for (int kc = 0; kc < 4; ++kc){
            v8s a = *(const v8s*)&Als[l15*136 + kc*32 + quad*8];
            for (int q = 0; q < 4; ++q){
                int nf = q*4 + w;
                v8s b = *(const v8s*)&encF[((nf*4 + kc)*64 + lane)*8];
                acc[q] = __builtin_amdgcn_mfma_f32_16x16x32_bf16(a, b, acc[q], 0, 0, 0);
            }
        }
        __syncthreads();
        for (int r = 0; r < 4; ++r){
            float gi = sigm(acc[0][r] + bi), gf = sigm(acc[1][r] + bff);
            float gg = tanh_(acc[2][r] + bg), go = sigm(acc[3][r] + bo);
            c4[r] = gf*c4[r] + gi*gg;
            Als[(quad*4 + r)*136 + 64 + j] = f2b(go*tanh_(c4[r]));
        }
        if (step < 7){
            int p = t>>4, e0 = (t&15)*4;
            float rx = b2f(rel[(step+1)*8192 + (pedbase+p)*2 + 0]);
            float ry = b2f(rel[(step+1)*8192 + (pedbase+p)*2 + 1]);
            for (int e = e0; e < e0+4; ++e)
                Als[p*136 + e] = f2b(rx*b2f(embW[e]) + ry*b2f(embW[64+e]) + b2f(embB[e]));
        }
    }
    __syncthreads();
    for (int idx = t; idx < 1024; idx += 256){
        int p = idx>>6, e = idx&63;
        ctxIn[(size_t)(pedbase+p)*1152 + e] = Als[p*136 + 64 + e];
    }
    {
        const int c0 = (t&127)*4, pg = (t>>7)*8;
        float4 acc[8];
        for (int p = 0; p < 8; ++p) acc[p] = make_float4(0.f,0.f,0.f,0.f);
        for (int e = 0; e < 64; ++e){
            ushort4 wv = *(const ushort4*)(IW1H + e*512 + c0);
            float w0 = b2f(wv.x), w1 = b2f(wv.y), w2 = b2f(wv.z), w3 = b2f(wv.w);
            for (int p = 0; p < 8; ++p){
                float h = b2f(Als[(pg+p)*136 + 64 + e]);
                acc[p].x += h*w0; acc[p].y += h*w1; acc[p].z += h*w2; acc[p].w += h*w3;
            }
        }
        float4 m0 = *(const float4*)(AUX + c0),        m1 = *(const float4*)(AUX + 512 + c0);
        float4 qv = *(const float4*)(AUX + 1024 + c0), cv = *(const float4*)(AUX + 1536 + c0);
        float4 g1 = *(const float4*)(AUX + 2048 + c0), bb = *(const float4*)(AUX + 2560 + c0);
        for (int p = 0; p < 8; ++p){
            float px = pxs[pg+p], py = pys[pg+p], sp = sps[pg+p];
            ushort4 o;
            o.x = f2b(g1.x*(px*m0.x + py*m1.x + sp*qv.x + cv.x + acc[p].x) + bb.x);
            o.y = f2b(g1.y*(px*m0.y + py*m1.y + sp*qv.y + cv.y + acc[p].y) + bb.y);
            o.z = f2b(g1.z*(px*m0.z + py*m1.z + sp*qv.z + cv.z + acc[p].z) + bb.z);
            o.w = f2b(g1.w*(px*m0.w + py*m1.w + sp*qv.w + cv.w + acc[p].w) + bb.w);
            *(ushort4*)&Avec[(size_t)(pedbase+pg+p)*512 + c0] = o;
        }
    }
    {
        int s = t & 63;
        for (int rep = 0; rep < 4; ++rep){
            int p = (t>>6)*4 + rep;
            int nid = pedbase + p;
            float a = b2f(sB[s]);
            for (int tt = 0; tt < 8; ++tt) a += b2f(IS[tt*4096 + nid]) * b2f(sW[tt*64 + s]);
            ctxIn[(size_t)nid*1152 + 1088 + s] = f2b(sigm(a));
        }
    }
}

// ---------------- pool GEMM v8 (split-launch): v4 structure + cheap A-build ----------------
__global__ __launch_bounds__(256, 3) void k_pool(
    const u16* __restrict__ Avec, const u16* __restrict__ W2T,
    const u16* __restrict__ IT, const float* __restrict__ AUX,
    u16* __restrict__ ctxIn, int xbase)
{
    __shared__ __align__(16) u16 Als[64*72];
    __shared__ __align__(16) u16 Bls[256*64];
    __shared__ __align__(16) float pmls[1024];
    const int t = threadIdx.x;
    const int bx = blockIdx.x + xbase;
    const int g = bx >> 4, ip = bx & 15;
    const int n0 = blockIdx.y * 256;
    const int w = t>>6, lane = t&63, quad = lane>>4, l15 = lane&15;
    const int aj = t>>3, ao = t&7;
    const float px0 = b2f(IT[7*8192 + (g*32 + ip*2 + 0)*2 + 0]);
    const float py0 = b2f(IT[7*8192 + (g*32 + ip*2 + 0)*2 + 1]);
    const float px1 = b2f(IT[7*8192 + (g*32 + ip*2 + 1)*2 + 0]);
    const float py1 = b2f(IT[7*8192 + (g*32 + ip*2 + 1)*2 + 1]);
    for (int i = t; i < 512; i += 256){
        float m0 = AUX[3072 + i], m1 = AUX[3584 + i];
        pmls[i]       = px0*m0 + py0*m1;
        pmls[512 + i] = px1*m0 + py1*m1;
    }
    const u16* bsrc = W2T + (size_t)(n0 + w*8 + (lane>>3))*512 + (size_t)(((lane&7) ^ (lane>>3)))*8;
    u16* bdst = &Bls[w*512];
    const u16* arow = Avec + (size_t)(g*32+aj)*512 + ao*8;
    v4f acc[4][4];
    for (int mf = 0; mf < 4; ++mf) for (int nf = 0; nf < 4; ++nf) acc[mf][nf] = (v4f){0.f,0.f,0.f,0.f};
    union { v8s v; u16 u[8]; } av;
    av.v = *(const v8s*)arow;
    for (int ch = 0; ch < 8; ++ch){
        const int k0 = ch*64;
        __syncthreads();
        for (int it = 0; it < 8; ++it)
            g2lds16(bsrc + k0 + it*16384, bdst + it*2048);
        {
            float a0[8];
            #pragma unroll
            for (int i = 0; i < 8; ++i) a0[i] = b2f(av.u[i]);
            #pragma unroll
            for (int il = 0; il < 2; ++il){
                float4 p0 = *(const float4*)&pmls[il*512 + k0 + ao*8];
                float4 p1 = *(const float4*)&pmls[il*512 + k0 + ao*8 + 4];
                float pmv[8] = {p0.x,p0.y,p0.z,p0.w,p1.x,p1.y,p1.z,p1.w};
                union { unsigned u[4]; v8s v; } pk;
                #pragma unroll
                for (int jj = 0; jj < 4; ++jj){
                    union { float f; unsigned u; } x0, x1;
                    x0.f = fmaxf(a0[2*jj]   - pmv[2*jj],   0.f);
                    x1.f = fmaxf(a0[2*jj+1] - pmv[2*jj+1], 0.f);
                    pk.u[jj] = __builtin_amdgcn_perm(x1.u + 0x8000u, x0.u + 0x8000u, 0x07060302u);
                }
                *(v8s*)&Als[(il*32+aj)*72 + ao*8] = pk.v;
            }
        }
        if (ch < 7) av.v = *(const v8s*)(arow + (ch+1)*64);
        __syncthreads();
        for (int kc = 0; kc < 2; ++kc){
            v8s af[4];
            for (int mf = 0; mf < 4; ++mf)
                af[mf] = *(const v8s*)&Als[(mf*16 + l15)*72 + kc*32 + quad*8];
            const int sl = ((kc*4 + quad) ^ (l15&7))*8;
            #pragma unroll
            for (int nf = 0; nf < 4; ++nf){
                v8s bf = *(const v8s*)&Bls[(w*64 + nf*16 + l15)*64 + sl];
                acc[0][nf] = __builtin_amdgcn_mfma_f32_16x16x32_bf16(af[0], bf, acc[0][nf], 0, 0, 0);
                acc[1][nf] = __builtin_amdgcn_mfma_f32_16x16x32_bf16(af[1], bf, acc[1][nf], 0, 0, 0);
                acc[2][nf] = __builtin_amdgcn_mfma_f32_16x16x32_bf16(af[2], bf, acc[2][nf], 0, 0, 0);
                acc[3][nf] = __builtin_amdgcn_mfma_f32_16x16x32_bf16(af[3], bf, acc[3][nf], 0, 0, 0);
            }
        }
    }
    const float* S2 = AUX + 4096; const float* B2 = AUX + 5120;
    for (int nf = 0; nf < 4; ++nf){
        int n = n0 + w*64 + nf*16 + l15;
        float s = S2[n], bb = B2[n];
        float mm0 = 0.f, mm1 = 0.f;
        for (int mf = 0; mf < 2; ++mf) for (int r = 0; r < 4; ++r) mm0 = fmaxf(mm0, fmaxf(s*acc[mf][nf][r] + bb, 0.f));
        for (int mf = 2; mf < 4; ++mf) for (int r = 0; r < 4; ++r) mm1 = fmaxf(mm1, fmaxf(s*acc[mf][nf][r] + bb, 0.f));
        mm0 = fmaxf(mm0, __shfl_xor(mm0, 16)); mm0 = fmaxf(mm0, __shfl_xor(mm0, 32));
        mm1 = fmaxf(mm1, __shfl_xor(mm1, 16)); mm1 = fmaxf(mm1, __shfl_xor(mm1, 32));
        if (quad == 0) ctxIn[(size_t)(g*32 + ip*2 + 0)*1152 + 64 + n] = f2b(mm0);
        if (quad == 1) ctxIn[(size_t)(g*32 + ip*2 + 1)*1152 + 64 + n] = f2b(mm1);
    }
}

// ---------------- generic MFMA GEMM, M-tile = MF*32: out = relu(S[n]*A@BT' + Bb[n]) ----------------
template<int MF>
__global__ __launch_bounds__(256) void k_gemm_bt(
    const u16* __restrict__ A, int lda, const u16* __restrict__ BT,
    const float* __restrict__ S, const float* __restrict__ Bb,
    u16* __restrict__ out, int ldo, int K, int validN,
    const u16* __restrict__ noisep)
{
    __shared__ __align__(16) u16 Als[MF*32*72];
    __shared__ __align__(16) u16 Bls[128*72];
    const int t = threadIdx.x;
    const int m0 = blockIdx.x*(MF*32), n0 = blockIdx.y*128;
    const int w = t>>6, lane = t&63, quad = lane>>4, l15 = lane&15;
    const int rw = w>>1, cw = w&1;
    v4f acc[MF][4];
    for (int mf = 0; mf < MF; ++mf) for (int nf = 0; nf < 4; ++nf) acc[mf][nf] = (v4f){0.f,0.f,0.f,0.f};
    const int nch = K >> 6;
    for (int ch = 0; ch < nch; ++ch){
        const int k0 = ch*64;
        __syncthreads();
        if (MF == 4){
            const int srow = t>>1, sh = t&1;
            const u16* srcA = A + (size_t)(m0+srow)*lda + k0 + sh*32;
            u16* dstA = &Als[srow*72 + sh*32];
            ((v8s*)dstA)[0] = ((const v8s*)srcA)[0];
            ((v8s*)dstA)[1] = ((const v8s*)srcA)[1];
            ((v8s*)dstA)[2] = ((const v8s*)srcA)[2];
            ((v8s*)dstA)[3] = ((const v8s*)srcA)[3];
        } else if (MF == 2){
            const int srow = t>>2, sh = t&3;
            const u16* srcA = A + (size_t)(m0+srow)*lda + k0 + sh*16;
            u16* dstA = &Als[srow*72 + sh*16];
            ((v8s*)dstA)[0] = ((const v8s*)srcA)[0];
            ((v8s*)dstA)[1] = ((const v8s*)srcA)[1];
        } else {
            const int srow = t>>3, sh = t&7;
            const u16* srcA = A + (size_t)(m0+srow)*lda + k0 + sh*8;
            u16* dstA = &Als[srow*72 + sh*8];
            ((v8s*)dstA)[0] = ((const v8s*)srcA)[0];
        }
        {
            const int srow = t>>1, sh = t&1;
            const u16* srcB = BT + (size_t)(n0+srow)*K + k0 + sh*32;
            u16* dstB = &Bls[srow*72 + sh*32];
            ((v8s*)dstB)[0] = ((const v8s*)srcB)[0];
            ((v8s*)dstB)[1] = ((const v8s*)srcB)[1];
            ((v8s*)dstB)[2] = ((const v8s*)srcB)[2];
            ((v8s*)dstB)[3] = ((const v8s*)srcB)[3];
        }
        __syncthreads();
        for (int kc = 0; kc < 2; ++kc){
            v8s af[MF], bf[4];
            for (int mf = 0; mf < MF; ++mf) af[mf] = *(const v8s*)&Als[(rw*(MF*16) + mf*16 + l15)*72 + kc*32 + quad*8];
            for (int nf = 0; nf < 4; ++nf) bf[nf] = *(const v8s*)&Bls[(cw*64 + nf*16 + l15)*72 + kc*32 + quad*8];
            for (int mf = 0; mf < MF; ++mf)
                for (int nf = 0; nf < 4; ++nf)
                    acc[mf][nf] = __builtin_amdgcn_mfma_f32_16x16x32_bf16(af[mf], bf[nf], acc[mf][nf], 0, 0, 0);
        }
    }
    for (int nf = 0; nf < 4; ++nf){
        int n = n0 + cw*64 + nf*16 + l15;
        bool okn = (n < validN);
        float s = okn ? S[n] : 0.f, bb = okn ? Bb[n] : 0.f;
        bool okz = (!okn) && (noisep != nullptr) && (n < 128);
        for (int mf = 0; mf < MF; ++mf){
            int m = m0 + rw*(MF*16) + mf*16 + quad*4;
            for (int r = 0; r < 4; ++r){
                float v = fmaxf(s*acc[mf][nf][r] + bb, 0.f);
                if (okn) out[(size_t)(m+r)*ldo + n] = f2b(v);
                else if (okz) out[(size_t)(m+r)*ldo + n] = noisep[(size_t)(m+r)*8 + (n - 120)];
            }
        }
    }
}

// ---------------- decoder LSTM rollout (barrier-trimmed) ----------------
__global__ __launch_bounds__(256) void k_decoder(
    const u16* __restrict__ decH0, const u16* __restrict__ decF, const u16* __restrict__ decB,
    const u16* __restrict__ dembW, const u16* __restrict__ dembB,
    const u16* __restrict__ h2pW, const u16* __restrict__ h2pB,
    const u16* __restrict__ obs_rel, const u16* __restrict__ obs_speed,
    const int* __restrict__ flag, void* __restrict__ outp)
{
    __shared__ __align__(16) u16 Als[16*200];
    __shared__ float sps[16];
    __shared__ float h2ps[256];
    const int t = threadIdx.x, pedbase = blockIdx.x*16;
    const int w = t>>6, lane = t&63, quad = lane>>4, l15 = lane&15;
    const int isf = *flag;
    for (int idx = t; idx < 2048; idx += 256){
        int p = idx>>7, jj = idx&127;
        Als[p*200 + 64 + jj] = decH0[(pedbase+p)*128 + jj];
    }
    h2ps[t] = b2f(h2pW[t]);
    if (t < 16) sps[t] = b2f(obs_speed[7*4096 + pedbase + t]);
    __syncthreads();
    {   // x0 from obs_rel directly
        int p = t>>4, e0 = (t&15)*4;
        float rx = b2f(obs_rel[7*8192 + (pedbase+p)*2 + 0]);
        float ry = b2f(obs_rel[7*8192 + (pedbase+p)*2 + 1]);
        for (int e = e0; e < e0+4; ++e){
            float v = rx*b2f(dembW[e]) + ry*b2f(dembW[64+e]) + sps[p]*b2f(dembW[128+e]) + b2f(dembB[e]);
            Als[p*200 + e] = f2b(v);
        }
    }
    float bI[2], bF[2], bG[2], bO[2];
    for (int nfl = 0; nfl < 2; ++nfl){
        int j = w*32 + nfl*16 + l15;
        bI[nfl] = b2f(decB[j]); bF[nfl] = b2f(decB[128+j]);
        bG[nfl] = b2f(decB[256+j]); bO[nfl] = b2f(decB[384+j]);
    }
    float c8[2][4] = {{0.f,0.f,0.f,0.f},{0.f,0.f,0.f,0.f}};
    for (int s = 0; s < 12; ++s){
        __syncthreads();
        v4f acc[4][2];
        for (int q = 0; q < 4; ++q) for (int nfl = 0; nfl < 2; ++nfl) acc[q][nfl] = (v4f){0.f,0.f,0.f,0.f};
        for (int kc = 0; kc < 6; ++kc){
            v8s a = *(const v8s*)&Als[l15*200 + kc*32 + quad*8];
            for (int q = 0; q < 4; ++q){
                for (int nfl = 0; nfl < 2; ++nfl){
                    int nf = q*8 + w*2 + nfl;
                    v8s b = *(const v8s*)&decF[((nf*6 + kc)*64 + lane)*8];
                    acc[q][nfl] = __builtin_amdgcn_mfma_f32_16x16x32_bf16(a, b, acc[q][nfl], 0, 0, 0);
                }
            }
        }
        __syncthreads();
        for (int nfl = 0; nfl < 2; ++nfl){
            int j = w*32 + nfl*16 + l15;
            for (int r = 0; r < 4; ++r){
                float gi = sigm(acc[0][nfl][r] + bI[nfl]), gf = sigm(acc[1][nfl][r] + bF[nfl]);
                float gg = tanh_(acc[2][nfl][r] + bG[nfl]), go = sigm(acc[3][nfl][r] + bO[nfl]);
                c8[nfl][r] = gf*c8[nfl][r] + gi*gg;
                Als[(quad*4 + r)*200 + 64 + j] = f2b(go*tanh_(c8[nfl][r]));
            }
        }
        __syncthreads();
        {   // h2p: partial sums over 16 jj, xor-reduce leaves full sum in all 8 part-lanes
            int p = t>>4, cmp = (t>>3)&1, part = t&7;
            float rp = 0.f;
            int j0 = part*16;
            for (int jj = j0; jj < j0+16; ++jj)
                rp += b2f(Als[p*200 + 64 + jj]) * h2ps[jj*2 + cmp];
            rp += __shfl_xor(rp, 1);
            rp += __shfl_xor(rp, 2);
            rp += __shfl_xor(rp, 4);
            rp += b2f(h2pB[cmp]);
            if (part == 0){
                int oi = s*8192 + (pedbase+p)*2 + cmp;
                if (isf) ((float*)outp)[oi] = rp;
                else     ((u16*)outp)[oi]   = f2b(rp);
            }
            // intra-wave broadcast of (rp0, rp1) to the 16-lane ped group
            float rp0 = __shfl(rp, (lane & 48));
            float rp1 = __shfl(rp, (lane & 48) + 8);
            if (s < 11){
                int e0 = (t&15)*4;
                for (int e = e0; e < e0+4; ++e){
                    float v = rp0*b2f(dembW[e]) + rp1*b2f(dembW[64+e]) + sps[p]*b2f(dembW[128+e]) + b2f(dembB[e]);
                    Als[p*200 + e] = f2b(v);
                }
            }
        }
    }
}

extern "C" void kernel_launch(void* const* d_in, const int* in_sizes, int n_in,
                              void* d_out, int out_size, void* d_ws, size_t ws_size,
                              hipStream_t stream)
{
    (void)in_sizes; (void)n_in; (void)out_size;
    const void* obs_traj  = d_in[0];
    const void* obs_rel   = d_in[1];
    const void* obs_speed = d_in[2];
    const void* noise     = d_in[3];
    const void* enc_emb_W = d_in[4];
    const void* enc_emb_b = d_in[5];
    const void* enc_Wih   = d_in[6];
    const void* enc_Whh   = d_in[7];
    const void* enc_b     = d_in[8];
    const void* pool_sp_W = d_in[9];
    const void* pool_sp_b = d_in[10];
    const void* pool_spd_W= d_in[11];
    const void* pool_spd_b= d_in[12];
    const void* pool_l1_W = d_in[13];
    const void* pool_l1_b = d_in[14];
    const void* pool_bn1_g= d_in[15];
    const void* pool_bn1_b= d_in[16];
    const void* pool_l2_W = d_in[17];
    const void* pool_l2_b = d_in[18];
    const void* pool_bn2_g= d_in[19];
    const void* pool_bn2_b= d_in[20];
    const void* spd_emb_W = d_in[21];
    const void* spd_emb_b = d_in[22];
    const void* ctx_l1_W  = d_in[23];
    const void* ctx_l1_b  = d_in[24];
    const void* ctx_bn1_g = d_in[25];
    const void* ctx_bn1_b = d_in[26];
    const void* ctx_l2_W  = d_in[27];
    const void* ctx_l2_b  = d_in[28];
    const void* ctx_bn2_g = d_in[29];
    const void* ctx_bn2_b = d_in[30];
    const void* dec_emb_W = d_in[31];
    const void* dec_emb_b = d_in[32];
    const void* dec_Wih   = d_in[33];
    const void* dec_Whh   = d_in[34];
    const void* dec_b     = d_in[35];
    const void* h2p_W     = d_in[36];
    const void* h2p_b     = d_in[37];

    char* ws = (char*)d_ws;
    int*   flag  = (int*)  (ws + FLAG_OFF);
    float* AUX   = (float*)(ws + AUX_OFF);
    u16*   encF  = (u16*)  (ws + ENCF_OFF);
    u16*   decF  = (u16*)  (ws + DECF_OFF);
    u16*   cW2T  = (u16*)  (ws + CW2T_OFF);
    u16*   W2T   = (u16*)  (ws + W2T_OFF);
    u16*   decH  = (u16*)  (ws + DECH_OFF);
    u16*   cW1T  = (u16*)  (ws + CW1T_OFF);
    u16*   IT    = (u16*)  (ws + IT_OFF);
    u16*   IR    = (u16*)  (ws + IR_OFF);
    u16*   IS    = (u16*)  (ws + IS_OFF);
    u16*   INZ   = (u16*)  (ws + INZ_OFF);
    u16*   IW1H  = (u16*)  (ws + IW1H_OFF);
    u16*   SM    = (u16*)  (ws + SM_OFF);
    u16*   ctxIn = (u16*)  (ws + CTX_OFF);
    u16*   Avec  = (u16*)  (ws + AV_OFF);
    u16*   c1    = (u16*)  (ws + AV_OFF);   // overlays Avec (dead after k_pool)
    const bool big = (ws_size >= (size_t)BIG_NEED);

    k_prep<<<dim3(1876), dim3(256), 0, stream>>>(
        obs_traj, obs_rel, obs_speed, noise,
        enc_emb_W, enc_emb_b, enc_Wih, enc_Whh, enc_b,
        pool_sp_W, pool_sp_b, pool_spd_W, pool_spd_b,
        pool_l1_W, pool_l1_b, pool_bn1_g, pool_bn1_b,
        pool_l2_W, pool_l2_b, pool_bn2_g, pool_bn2_b,
        spd_emb_W, spd_emb_b,
        ctx_l1_W, ctx_l1_b, ctx_bn1_g, ctx_bn1_b,
        ctx_l2_W, ctx_l2_b, ctx_bn2_g, ctx_bn2_b,
        dec_emb_W, dec_emb_b, dec_Wih, dec_Whh, dec_b,
        h2p_W, h2p_b,
        flag, AUX, IT, IR, IS, INZ, IW1H, SM,
        W2T, cW1T, cW2T, encF, decF);
    k_encoder<<<dim3(256), dim3(256), 0, stream>>>(
        IR, SM + SM_EEW, SM + SM_EEB, encF, SM + SM_ENB,
        IT, IS, IW1H, SM + SM_SEW, SM + SM_SEB, AUX, ctxIn, Avec);
    k_pool<<<dim3(1024, 4), dim3(256), 0, stream>>>(Avec, W2T, IT, AUX, ctxIn, 0);
    k_pool<<<dim3(1024, 4), dim3(256), 0, stream>>>(Avec, W2T, IT, AUX, ctxIn, 1024);
    if (big){
        k_gemm_bt<2><<<dim3(64, 8), dim3(256), 0, stream>>>(
            ctxIn, 1152, cW1T, AUX + 6144, AUX + 7168, c1, 1024, 1152, 1024, (const u16*)nullptr);
        k_gemm_bt<1><<<dim3(128, 1), dim3(256), 0, stream>>>(
            c1, 1024, cW2T, AUX + 8192, AUX + 8320, decH, 128, 1024, 120, INZ);
    } else {
        k_gemm_bt<2><<<dim3(32, 8), dim3(256), 0, stream>>>(
            ctxIn, 1152, cW1T, AUX + 6144, AUX + 7168, c1, 1024, 1152, 1024, (const u16*)nullptr);
        k_gemm_bt<1><<<dim3(64, 1), dim3(256), 0, stream>>>(
            c1, 1024, cW2T, AUX + 8192, AUX + 8320, decH, 128, 1024, 120, INZ);
        k_gemm_bt<2><<<dim3(32, 8), dim3(256), 0, stream>>>(
            ctxIn + (size_t)2048*1152, 1152, cW1T, AUX + 6144, AUX + 7168, c1, 1024, 1152, 1024, (const u16*)nullptr);
        k_gemm_bt<1><<<dim3(64, 1), dim3(256), 0, stream>>>(
            c1, 1024, cW2T, AUX + 8192, AUX + 8320, decH + (size_t)2048*128, 128, 1024, 120, INZ + (size_t)2048*8);
    }
    k_decoder<<<dim3(256), dim3(256), 0, stream>>>(
        decH, decF, SM + SM_DNB, SM + SM_DEW, SM + SM_DEB,
        SM + SM_H2W, SM + SM_H2B, IR, IS, flag, d_out);
}